// Round 18
// baseline (1737.734 us; speedup 1.0000x reference)
//
#include <hip/hip_runtime.h>
#include <math.h>

// ---- problem dims ----
#define Bq    2
#define Dq    512
#define DFFq  2048
#define Lq    6
#define NHq   8
#define HDq   64
#define Kq    8192
#define Sq    784
#define PINq  3072
#define TOKq  1568
#define RECN  4816896L

// ---- workspace layout (float offsets) ----
#define OFF_BIG  0L
#define SZ_BIG   12845056L
#define OFF_Z    (OFF_BIG + SZ_BIG)
#define OFF_XLN  (OFF_Z    + 802816L)
#define OFF_QKV  (OFF_XLN  + 802816L)
#define OFF_ATTO (OFF_QKV  + 2408448L)
#define OFF_H    (OFF_ATTO + 802816L)
#define OFF_ZE   (OFF_H    + 3211264L)
#define OFF_ZQ   (OFF_ZE   + 802816L)
#define OFF_CN   (OFF_ZQ   + 802816L)
#define OFF_IDX  (OFF_CN   + 8192L)
#define OFF_CNT  (OFF_IDX  + 1568L)
#define OFF_PART (OFF_CNT  + 8192L)
#define OFF_MIN  (OFF_PART + 1568L)
#define OFF_END  (OFF_MIN  + 3136L)

#define CEXT 802816L

typedef short bf16x8 __attribute__((ext_vector_type(8)));
typedef float f32x4  __attribute__((ext_vector_type(4)));
typedef unsigned short u16;
typedef unsigned long long u64;

// plane offsets (u16 elements)
#define XLO 802816L
#define QLO 2408448L
#define ALO 802816L
#define HLO 3211264L
#define PLO 4816896L
#define ZLO 802816L
#define CBLO 4194304L

// ================= helpers =================
__device__ __forceinline__ float wave_sum(float v) {
    #pragma unroll
    for (int o = 32; o; o >>= 1) v += __shfl_xor(v, o);
    return v;
}
__device__ __forceinline__ float gelu_f(float x) {
    float u = 0.7978845608028654f * (x + 0.044715f * x * x * x);
    float a = fabsf(u);
    float t = __expf(-2.0f * a);
    float th = (1.0f - t) / (1.0f + t);
    th = copysignf(th, u);
    return 0.5f * x * (1.0f + th);
}
__device__ __forceinline__ void split_f32(float x, u16& h, u16& l) {
    unsigned u = __float_as_uint(x);
    unsigned t = u + 0x7fffu + ((u >> 16) & 1u);
    h = (u16)(t >> 16);
    float r = x - __uint_as_float((t >> 16) << 16);
    l = (u16)(__float_as_uint(r) >> 16);
}
__device__ __forceinline__ void gload16(const u16* g, u16* l) {
    __builtin_amdgcn_global_load_lds(
        (const __attribute__((address_space(1))) void*)g,
        (__attribute__((address_space(3))) void*)l,
        16, 0, 0);
}

// ================= single weight convert+transpose =================
__global__ __launch_bounds__(256)
void wconv_t(const float* __restrict__ W, int ldw, int Kd,
             u16* __restrict__ WT, long loT, long soW, long soT)
{
    __shared__ u16 Lh[32][33], Ll[32][33];
    const float* Wp = W + (long)blockIdx.z * soW;
    u16* Tp = WT + (long)blockIdx.z * soT;
    int k0 = blockIdx.x << 5, n0 = blockIdx.y << 5;
    int t = threadIdx.x;
    int r = t >> 3, c4 = (t & 7) << 2;
    float4 v = *(const float4*)(Wp + (long)(k0 + r) * ldw + n0 + c4);
    u16 h, l;
    split_f32(v.x, h, l); Lh[c4+0][r] = h; Ll[c4+0][r] = l;
    split_f32(v.y, h, l); Lh[c4+1][r] = h; Ll[c4+1][r] = l;
    split_f32(v.z, h, l); Lh[c4+2][r] = h; Ll[c4+2][r] = l;
    split_f32(v.w, h, l); Lh[c4+3][r] = h; Ll[c4+3][r] = l;
    __syncthreads();
    int n = t >> 3, kc = (t & 7) << 2;
    u16* dst = Tp + (long)(n0 + n) * Kd + k0 + kc;
    u16 oh[4] = {Lh[n][kc], Lh[n][kc+1], Lh[n][kc+2], Lh[n][kc+3]};
    u16 ol[4] = {Ll[n][kc], Ll[n][kc+1], Ll[n][kc+2], Ll[n][kc+3]};
    *(uint2*)dst = *(uint2*)oh;
    *(uint2*)(dst + loT) = *(uint2*)ol;
}

// ================= all-4 layer weights in one launch =================
__global__ __launch_bounds__(256)
void wconv4(const float* __restrict__ Wqkv, const float* __restrict__ Wo,
            const float* __restrict__ W1, const float* __restrict__ W2,
            u16* __restrict__ dst)
{
    __shared__ u16 Lh[32][33], Ll[32][33];
    int id = blockIdx.x;
    const float* W; int ldw, Kd, kblk, nblk; u16* Tp; long loT;
    if (id < 768) {
        int z = id >> 8, rid = id & 255;
        kblk = rid & 15; nblk = rid >> 4;
        W = Wqkv + (long)z * 262144; ldw = 512; Kd = 512;
        Tp = dst + (long)z * 262144; loT = 786432;
    } else if (id < 1024) {
        int rid = id - 768; kblk = rid & 15; nblk = rid >> 4;
        W = Wo; ldw = 512; Kd = 512; Tp = dst + 1572864; loT = 262144;
    } else if (id < 2048) {
        int rid = id - 1024; kblk = rid & 15; nblk = rid >> 4;
        W = W1; ldw = 2048; Kd = 512; Tp = dst + 2097152; loT = 1048576;
    } else {
        int rid = id - 2048; kblk = rid & 63; nblk = rid >> 6;
        W = W2; ldw = 512; Kd = 2048; Tp = dst + 4194304; loT = 1048576;
    }
    int k0 = kblk << 5, n0 = nblk << 5;
    int t = threadIdx.x;
    int r = t >> 3, c4 = (t & 7) << 2;
    float4 v = *(const float4*)(W + (long)(k0 + r) * ldw + n0 + c4);
    u16 h, l;
    split_f32(v.x, h, l); Lh[c4+0][r] = h; Ll[c4+0][r] = l;
    split_f32(v.y, h, l); Lh[c4+1][r] = h; Ll[c4+1][r] = l;
    split_f32(v.z, h, l); Lh[c4+2][r] = h; Ll[c4+2][r] = l;
    split_f32(v.w, h, l); Lh[c4+3][r] = h; Ll[c4+3][r] = l;
    __syncthreads();
    int n = t >> 3, kc = (t & 7) << 2;
    u16* d = Tp + (long)(n0 + n) * Kd + k0 + kc;
    u16 oh[4] = {Lh[n][kc], Lh[n][kc+1], Lh[n][kc+2], Lh[n][kc+3]};
    u16 ol[4] = {Ll[n][kc], Ll[n][kc+1], Ll[n][kc+2], Ll[n][kc+3]};
    *(uint2*)d = *(uint2*)oh;
    *(uint2*)(d + loT) = *(uint2*)ol;
}

// ================= codebook prep: norms + planar split in one pass =================
__global__ __launch_bounds__(256)
void cbprep(const float* __restrict__ cb, float* __restrict__ cn, u16* __restrict__ cbs)
{
    int wave = threadIdx.x >> 6, lane = threadIdx.x & 63;
    int row = (blockIdx.x << 2) + wave;
    const float* cr = cb + (long)row * Dq;
    int c0 = lane << 3;
    float4 v0 = *(const float4*)(cr + c0);
    float4 v1 = *(const float4*)(cr + c0 + 4);
    float ss = v0.x*v0.x+v0.y*v0.y+v0.z*v0.z+v0.w*v0.w
             + v1.x*v1.x+v1.y*v1.y+v1.z*v1.z+v1.w*v1.w;
    ss = wave_sum(ss);
    if (lane == 0) cn[row] = ss;
    u16 h[8], l[8];
    split_f32(v0.x, h[0], l[0]); split_f32(v0.y, h[1], l[1]);
    split_f32(v0.z, h[2], l[2]); split_f32(v0.w, h[3], l[3]);
    split_f32(v1.x, h[4], l[4]); split_f32(v1.y, h[5], l[5]);
    split_f32(v1.z, h[6], l[6]); split_f32(v1.w, h[7], l[7]);
    *(uint4*)(cbs + (long)row * Dq + c0) = *(uint4*)h;
    *(uint4*)(cbs + CBLO + (long)row * Dq + c0) = *(uint4*)l;
}

// ================= 64x64 MFMA GEMM, BK=64, chunk-swizzled LDS =================
// LV=3: bf16x3. LV=2: A hi+lo, B hi. LV=1: pure bf16.
// MATH 0: f32 alpha*acc+bias; 2: planar gelu(acc+bias); 3: f32 (acc+bias) AND planar;
// 4: planar acc+bias; 6: acc+bias scattered to recon (unpatchify fused).
template<int MATH, int LV>
__global__ __launch_bounds__(256)
void gemm_bb(const u16* __restrict__ A, long rsA, long loA, long soA, long siA,
             const u16* __restrict__ B, long rsB, long loB, long soB, long siB,
             const float* __restrict__ bias, long siBias,
             const float* __restrict__ extra,
             float* __restrict__ Cf, int ldc, long soC, long siC,
             u16* __restrict__ Cb, int rsC, long loC,
             float* __restrict__ part, long pstride,
             int M, int N, int K, float alpha,
             int bdiv, int ksplit, int klen, int gx)
{
    constexpr int OFF_BH = (LV >= 2) ? 8192 : 4096;
    __shared__ u16 SH[LV == 3 ? 16384 : (LV == 2 ? 12288 : 8192)];
    const int zb2 = blockIdx.z;
    const int zk = zb2 % ksplit, zb = zb2 / ksplit;
    const int zo = zb / bdiv, zi = zb - zo * bdiv;
    A += zo * soA + zi * siA;
    B += zo * soB + zi * siB;
    const float* bi = bias ? bias + zi * siBias : nullptr;

    const int nwg = gridDim.x;
    int orig = blockIdx.x;
    int qq = nwg >> 3, rr = nwg & 7;
    int xcd = orig & 7, sidx = orig >> 3;
    int wgid = (xcd < rr ? xcd * (qq + 1) : rr * (qq + 1) + (xcd - rr) * qq) + sidx;
    const int m0 = (wgid % gx) << 6, n0 = (wgid / gx) << 6;

    const int t = threadIdx.x;
    const int kbeg = zk * klen;
    int kend = kbeg + klen; if (kend > K) kend = K;

    const int w = t >> 6, lane = t & 63;
    const int wm = w >> 1, wn = w & 1;
    const int l15 = lane & 15, g = lane >> 4;
    const int wq = w << 9;

    const int csrc = ((t & 3) + ((t >> 3) & 7)) & 3;
    int arow = m0 + (t >> 2); if (arow > M - 1) arow = M - 1;
    const u16* Apr = A + (long)arow * rsA + (csrc << 3);
    const u16* Bpr = B + (long)(n0 + (t >> 2)) * rsB + (csrc << 3);

    f32x4 acc[2][2] = {};

    for (int k0 = kbeg; k0 < kend; k0 += 64) {
        gload16(Apr + k0,            &SH[wq]);
        if (LV >= 2) gload16(Apr + k0 + loA,      &SH[4096 + wq]);
        gload16(Bpr + k0,            &SH[OFF_BH + wq]);
        if (LV == 3) gload16(Bpr + k0 + loB, &SH[12288 + wq]);
        gload16(Apr + k0 + 32,       &SH[2048 + wq]);
        if (LV >= 2) gload16(Apr + k0 + 32 + loA, &SH[4096 + 2048 + wq]);
        gload16(Bpr + k0 + 32,       &SH[OFF_BH + 2048 + wq]);
        if (LV == 3) gload16(Bpr + k0 + 32 + loB, &SH[12288 + 2048 + wq]);
        __syncthreads();

        #pragma unroll
        for (int sub = 0; sub < 2; ++sub) {
            const int so = sub << 11;
            bf16x8 ah[2], al2[2], bh2[2], bl2[2];
            #pragma unroll
            for (int mi = 0; mi < 2; ++mi) {
                int row = (wm << 5) + (mi << 4) + l15;
                int off = (row << 5) + (((g - (row >> 1)) & 3) << 3);
                ah[mi]  = *(const bf16x8*)&SH[so + off];
                if (LV >= 2) al2[mi] = *(const bf16x8*)&SH[4096 + so + off];
            }
            #pragma unroll
            for (int ni = 0; ni < 2; ++ni) {
                int row = (wn << 5) + (ni << 4) + l15;
                int off = (row << 5) + (((g - (row >> 1)) & 3) << 3);
                bh2[ni] = *(const bf16x8*)&SH[OFF_BH + so + off];
                if (LV == 3) bl2[ni] = *(const bf16x8*)&SH[12288 + so + off];
            }
            #pragma unroll
            for (int mi = 0; mi < 2; ++mi)
                #pragma unroll
                for (int ni = 0; ni < 2; ++ni) {
                    acc[mi][ni] = __builtin_amdgcn_mfma_f32_16x16x32_bf16(ah[mi], bh2[ni], acc[mi][ni], 0, 0, 0);
                    if (LV == 3) acc[mi][ni] = __builtin_amdgcn_mfma_f32_16x16x32_bf16(ah[mi], bl2[ni], acc[mi][ni], 0, 0, 0);
                    if (LV >= 2) acc[mi][ni] = __builtin_amdgcn_mfma_f32_16x16x32_bf16(al2[mi], bh2[ni], acc[mi][ni], 0, 0, 0);
                }
        }
        __syncthreads();
    }

    if (ksplit > 1) {
        float* P = part + (long)zk * pstride + zo * soC + zi * siC;
        #pragma unroll
        for (int mi = 0; mi < 2; ++mi)
            #pragma unroll
            for (int ni = 0; ni < 2; ++ni) {
                int gn = n0 + (wn << 5) + (ni << 4) + l15;
                if (gn >= N) continue;
                int gmb = m0 + (wm << 5) + (mi << 4) + (g << 2);
                #pragma unroll
                for (int r = 0; r < 4; ++r) {
                    int gm = gmb + r;
                    if (gm < M) P[(long)gm * ldc + gn] = acc[mi][ni][r];
                }
            }
        return;
    }
    if (MATH == 0) {
        float* Co = Cf + zo * soC + zi * siC;
        #pragma unroll
        for (int mi = 0; mi < 2; ++mi)
            #pragma unroll
            for (int ni = 0; ni < 2; ++ni) {
                int gn = n0 + (wn << 5) + (ni << 4) + l15;
                if (gn >= N) continue;
                int gmb = m0 + (wm << 5) + (mi << 4) + (g << 2);
                #pragma unroll
                for (int r = 0; r < 4; ++r) {
                    int gm = gmb + r;
                    if (gm >= M) continue;
                    Co[(long)gm * ldc + gn] = alpha * acc[mi][ni][r] + (bi ? bi[gn] : 0.0f);
                }
            }
    } else if (MATH == 3) {
        #pragma unroll
        for (int mi = 0; mi < 2; ++mi)
            #pragma unroll
            for (int ni = 0; ni < 2; ++ni) {
                int gn = n0 + (wn << 5) + (ni << 4) + l15;
                if (gn >= N) continue;
                int gmb = m0 + (wm << 5) + (mi << 4) + (g << 2);
                #pragma unroll
                for (int r = 0; r < 4; ++r) {
                    int gm = gmb + r;
                    if (gm >= M) continue;
                    float v = acc[mi][ni][r] + bi[gn];
                    Cf[(long)gm * ldc + gn] = v;
                    u16 h, l; split_f32(v, h, l);
                    Cb[(long)gm * rsC + gn] = h;
                    Cb[(long)gm * rsC + gn + loC] = l;
                }
            }
    } else if (MATH == 6) {
        // fused unpatchify scatter: Cf = recon base
        #pragma unroll
        for (int mi = 0; mi < 2; ++mi)
            #pragma unroll
            for (int ni = 0; ni < 2; ++ni) {
                int gn = n0 + (wn << 5) + (ni << 4) + l15;
                if (gn >= N) continue;
                int c = gn % 3; int q = gn / 3;
                int pw = q & 15, ph = (q >> 4) & 15, tpin = q >> 8;
                int gmb = m0 + (wm << 5) + (mi << 4) + (g << 2);
                #pragma unroll
                for (int r = 0; r < 4; ++r) {
                    int gm = gmb + r;
                    if (gm >= M) continue;
                    float v = acc[mi][ni][r] + bi[gn];
                    int wp = gm % 14; int t1 = gm / 14;
                    int hp = t1 % 14; int t2 = t1 / 14;
                    int tp = t2 & 3, b = t2 >> 2;
                    long o = ((((long)(b * 16 + tp * 4 + tpin) * 224) + hp * 16 + ph) * 224 + wp * 16 + pw) * 3 + c;
                    Cf[o] = v;
                }
            }
    } else {
        u16* Cu = Cb + zo * soC + zi * siC;
        #pragma unroll
        for (int mi = 0; mi < 2; ++mi)
            #pragma unroll
            for (int ni = 0; ni < 2; ++ni) {
                int gn = n0 + (wn << 5) + (ni << 4) + l15;
                if (gn >= N) continue;
                int gmb = m0 + (wm << 5) + (mi << 4) + (g << 2);
                #pragma unroll
                for (int r = 0; r < 4; ++r) {
                    int gm = gmb + r;
                    if (gm >= M) continue;
                    float v = acc[mi][ni][r] + bi[gn];
                    if (MATH == 2) v = gelu_f(v);
                    u16 h, l; split_f32(v, h, l);
                    Cu[(long)gm * rsC + gn] = h;
                    Cu[(long)gm * rsC + gn + loC] = l;
                }
            }
    }
}

// ================= d2 VQ GEMM: 64x128 block, bf16x3, fused argmin =================
__global__ __launch_bounds__(256)
void gemm_d2w(const u16* __restrict__ A, long rsA, long loA,
              const u16* __restrict__ B, long rsB, long loB,
              const float* __restrict__ extra, u64* __restrict__ mb,
              int M, int N, int K, int gx)
{
    __shared__ u16 SH[24576];
    const int nwg = gridDim.x;
    int orig = blockIdx.x;
    int qq = nwg >> 3, rr = nwg & 7;
    int xcd = orig & 7, sidx = orig >> 3;
    int wgid = (xcd < rr ? xcd * (qq + 1) : rr * (qq + 1) + (xcd - rr) * qq) + sidx;
    const int m0 = (wgid % gx) << 6, n0 = (wgid / gx) << 7;

    const int t = threadIdx.x;
    const int w = t >> 6, lane = t & 63;
    const int wm = w >> 1, wn = w & 1;
    const int l15 = lane & 15, g = lane >> 4;
    const int wq = w << 9;

    const int csrc = ((t & 3) + ((t >> 3) & 7)) & 3;
    int arow = m0 + (t >> 2); if (arow > M - 1) arow = M - 1;
    const u16* Apr = A + (long)arow * rsA + (csrc << 3);
    const u16* Bpr0 = B + (long)(n0 + (t >> 2)) * rsB + (csrc << 3);
    const u16* Bpr1 = B + (long)(n0 + 64 + (t >> 2)) * rsB + (csrc << 3);

    f32x4 acc[2][4] = {};

    for (int k0 = 0; k0 < K; k0 += 64) {
        gload16(Apr + k0,             &SH[wq]);
        gload16(Apr + k0 + 32,        &SH[2048 + wq]);
        gload16(Apr + k0 + loA,       &SH[4096 + wq]);
        gload16(Apr + k0 + 32 + loA,  &SH[4096 + 2048 + wq]);
        gload16(Bpr0 + k0,            &SH[8192 + wq]);
        gload16(Bpr1 + k0,            &SH[8192 + 2048 + wq]);
        gload16(Bpr0 + k0 + 32,       &SH[12288 + wq]);
        gload16(Bpr1 + k0 + 32,       &SH[12288 + 2048 + wq]);
        gload16(Bpr0 + k0 + loB,      &SH[16384 + wq]);
        gload16(Bpr1 + k0 + loB,      &SH[16384 + 2048 + wq]);
        gload16(Bpr0 + k0 + 32 + loB, &SH[20480 + wq]);
        gload16(Bpr1 + k0 + 32 + loB, &SH[20480 + 2048 + wq]);
        __syncthreads();

        #pragma unroll
        for (int sub = 0; sub < 2; ++sub) {
            const int soA = sub << 11;
            const int soB = sub << 12;
            bf16x8 ah[2], al2[2], bh2[4], bl2[4];
            #pragma unroll
            for (int mi = 0; mi < 2; ++mi) {
                int row = (wm << 5) + (mi << 4) + l15;
                int off = (row << 5) + (((g - (row >> 1)) & 3) << 3);
                ah[mi]  = *(const bf16x8*)&SH[soA + off];
                al2[mi] = *(const bf16x8*)&SH[4096 + soA + off];
            }
            #pragma unroll
            for (int ni = 0; ni < 4; ++ni) {
                int row = (wn << 6) + (ni << 4) + l15;
                int off = (row << 5) + (((g - (row >> 1)) & 3) << 3);
                bh2[ni] = *(const bf16x8*)&SH[8192 + soB + off];
                bl2[ni] = *(const bf16x8*)&SH[16384 + soB + off];
            }
            #pragma unroll
            for (int mi = 0; mi < 2; ++mi)
                #pragma unroll
                for (int ni = 0; ni < 4; ++ni) {
                    acc[mi][ni] = __builtin_amdgcn_mfma_f32_16x16x32_bf16(ah[mi],  bh2[ni], acc[mi][ni], 0, 0, 0);
                    acc[mi][ni] = __builtin_amdgcn_mfma_f32_16x16x32_bf16(ah[mi],  bl2[ni], acc[mi][ni], 0, 0, 0);
                    acc[mi][ni] = __builtin_amdgcn_mfma_f32_16x16x32_bf16(al2[mi], bh2[ni], acc[mi][ni], 0, 0, 0);
                }
        }
        __syncthreads();
    }

    #pragma unroll
    for (int mi = 0; mi < 2; ++mi) {
        #pragma unroll
        for (int r = 0; r < 4; ++r) {
            u64 best = 0xFFFFFFFFFFFFFFFFULL;
            #pragma unroll
            for (int ni = 0; ni < 4; ++ni) {
                int gn = n0 + (wn << 6) + (ni << 4) + l15;
                float v = extra[gn] - 2.0f * acc[mi][ni][r];
                unsigned ub = __float_as_uint(v);
                ub = ub ^ ((ub >> 31) ? 0xFFFFFFFFu : 0x80000000u);
                u64 pk = ((u64)ub << 32) | (unsigned)gn;
                best = pk < best ? pk : best;
            }
            #pragma unroll
            for (int sft = 1; sft <= 8; sft <<= 1) {
                u64 o = __shfl_xor(best, sft);
                best = o < best ? o : best;
            }
            if (l15 == 0) {
                int gm = m0 + (wm << 5) + (mi << 4) + (g << 2) + r;
                if (gm < M) atomicMin(&mb[gm], best);
            }
        }
    }
}

// ================= flash attention, KV-split x4 =================
#define KP 72
#define VP 40
#define CHR 196
template<bool X2>
__global__ __launch_bounds__(256)
void flash_kernel(const u16* __restrict__ qkv, float* __restrict__ O4, float* __restrict__ ML)
{
    __shared__ u16 Kh[32 * KP], Kl[32 * KP];
    __shared__ u16 Vh[64 * VP], Vl[64 * VP];
    __shared__ u16 Ph[64 * VP], Pl[64 * VP];

    const int qb = blockIdx.x, bh = blockIdx.y, ch = blockIdx.z;
    const int b = bh >> 3, h = bh & 7;
    const int jbeg = ch * CHR, jend = jbeg + CHR;
    const int t = threadIdx.x, w = t >> 6, lane = t & 63;
    const int l15 = lane & 15, g = lane >> 4;
    const long base = (long)b * 784 * 1536;
    const u16* Qg = qkv + base + h * 64;
    const u16* Kg = qkv + base + 512 + h * 64;
    const u16* Vg = qkv + base + 1024 + h * 64;

    const int q0 = qb << 6;
    int qr = q0 + w * 16 + l15; if (qr > 783) qr = 783;
    const u16* Qp = Qg + (long)qr * 1536 + g * 8;
    bf16x8 qh[2], ql[2];
    qh[0] = *(const bf16x8*)(Qp);
    qh[1] = *(const bf16x8*)(Qp + 32);
    ql[0] = *(const bf16x8*)(Qp + QLO);
    ql[1] = *(const bf16x8*)(Qp + QLO + 32);

    f32x4 O[4] = {};
    float m_[4] = {-1e30f, -1e30f, -1e30f, -1e30f};
    float l_[4] = {};

    const int srow = t >> 3, sc = (t & 7) << 3;

    for (int j0 = jbeg; j0 < jend; j0 += 32) {
        {
            int jr = j0 + srow;
            if (jr < jend) {
                const u16* Kp = Kg + (long)jr * 1536 + sc;
                *(uint4*)&Kh[srow * KP + sc] = *(const uint4*)(Kp);
                if (!X2) *(uint4*)&Kl[srow * KP + sc] = *(const uint4*)(Kp + QLO);
                const u16* Vp = Vg + (long)jr * 1536 + sc;
                u16 th[8], tl[8];
                *(uint4*)th = *(const uint4*)Vp;
                if (!X2) *(uint4*)tl = *(const uint4*)(Vp + QLO);
                #pragma unroll
                for (int e = 0; e < 8; ++e) {
                    Vh[(sc + e) * VP + srow] = th[e];
                    if (!X2) Vl[(sc + e) * VP + srow] = tl[e];
                }
            } else {
                uint4 zz = {0, 0, 0, 0};
                *(uint4*)&Kh[srow * KP + sc] = zz;
                if (!X2) *(uint4*)&Kl[srow * KP + sc] = zz;
                #pragma unroll
                for (int e = 0; e < 8; ++e) {
                    Vh[(sc + e) * VP + srow] = 0;
                    if (!X2) Vl[(sc + e) * VP + srow] = 0;
                }
            }
        }
        __syncthreads();

        f32x4 S[2] = {};
        #pragma unroll
        for (int f = 0; f < 2; ++f) {
            #pragma unroll
            for (int ks = 0; ks < 2; ++ks) {
                bf16x8 kh = *(const bf16x8*)&Kh[(f * 16 + l15) * KP + ks * 32 + g * 8];
                S[f] = __builtin_amdgcn_mfma_f32_16x16x32_bf16(qh[ks], kh, S[f], 0, 0, 0);
                if (!X2) {
                    bf16x8 kl = *(const bf16x8*)&Kl[(f * 16 + l15) * KP + ks * 32 + g * 8];
                    S[f] = __builtin_amdgcn_mfma_f32_16x16x32_bf16(qh[ks], kl, S[f], 0, 0, 0);
                }
                S[f] = __builtin_amdgcn_mfma_f32_16x16x32_bf16(ql[ks], kh, S[f], 0, 0, 0);
            }
        }

        float p[2][4];
        #pragma unroll
        for (int f = 0; f < 2; ++f) {
            bool ok = (j0 + f * 16 + l15) < jend;
            #pragma unroll
            for (int r = 0; r < 4; ++r)
                p[f][r] = ok ? S[f][r] * 0.125f : -1e30f;
        }
        #pragma unroll
        for (int r = 0; r < 4; ++r) {
            float pm = fmaxf(p[0][r], p[1][r]);
            pm = fmaxf(pm, __shfl_xor(pm, 1)); pm = fmaxf(pm, __shfl_xor(pm, 2));
            pm = fmaxf(pm, __shfl_xor(pm, 4)); pm = fmaxf(pm, __shfl_xor(pm, 8));
            float mn = fmaxf(m_[r], pm);
            float scl = __expf(m_[r] - mn);
            float rs = 0.f;
            #pragma unroll
            for (int f = 0; f < 2; ++f) { float e = __expf(p[f][r] - mn); p[f][r] = e; rs += e; }
            rs += __shfl_xor(rs, 1); rs += __shfl_xor(rs, 2);
            rs += __shfl_xor(rs, 4); rs += __shfl_xor(rs, 8);
            l_[r] = l_[r] * scl + rs;
            m_[r] = mn;
            O[0][r] *= scl; O[1][r] *= scl; O[2][r] *= scl; O[3][r] *= scl;
        }

        #pragma unroll
        for (int f = 0; f < 2; ++f)
            #pragma unroll
            for (int r = 0; r < 4; ++r) {
                u16 hh, ll; split_f32(p[f][r], hh, ll);
                int row = w * 16 + g * 4 + r;
                Ph[row * VP + f * 16 + l15] = hh;
                Pl[row * VP + f * 16 + l15] = ll;
            }

        bf16x8 pah = *(const bf16x8*)&Ph[(w * 16 + l15) * VP + g * 8];
        bf16x8 pal = *(const bf16x8*)&Pl[(w * 16 + l15) * VP + g * 8];
        #pragma unroll
        for (int f = 0; f < 4; ++f) {
            bf16x8 vh = *(const bf16x8*)&Vh[(f * 16 + l15) * VP + g * 8];
            O[f] = __builtin_amdgcn_mfma_f32_16x16x32_bf16(pah, vh, O[f], 0, 0, 0);
            O[f] = __builtin_amdgcn_mfma_f32_16x16x32_bf16(pal, vh, O[f], 0, 0, 0);
            if (!X2) {
                bf16x8 vl = *(const bf16x8*)&Vl[(f * 16 + l15) * VP + g * 8];
                O[f] = __builtin_amdgcn_mfma_f32_16x16x32_bf16(pah, vl, O[f], 0, 0, 0);
            }
        }
        __syncthreads();
    }

    #pragma unroll
    for (int r = 0; r < 4; ++r) {
        int q = q0 + w * 16 + g * 4 + r;
        if (q >= 784) continue;
        long rowi = ((long)ch * 16 + bh) * 784 + q;
        if (l15 == 0) { ML[rowi * 2] = m_[r]; ML[rowi * 2 + 1] = l_[r]; }
        #pragma unroll
        for (int f = 0; f < 4; ++f)
            O4[rowi * 64 + f * 16 + l15] = O[f][r];
    }
}

// ================= flash combine: merge 4 KV-chunk partials =================
__global__ __launch_bounds__(256)
void flash_combine(const float* __restrict__ O4, const float* __restrict__ ML,
                   u16* __restrict__ atto)
{
    int wave = threadIdx.x >> 6, lane = threadIdx.x & 63;
    int row = (blockIdx.x << 2) + wave;
    int bh = row / 784, q = row - bh * 784;
    int b = bh >> 3, h = bh & 7;
    float mm[4], ll[4];
    float M = -1e30f;
    #pragma unroll
    for (int c = 0; c < 4; ++c) {
        long ri = ((long)c * 16 + bh) * 784 + q;
        mm[c] = ML[ri * 2]; ll[c] = ML[ri * 2 + 1];
        M = fmaxf(M, mm[c]);
    }
    float L = 0.f, sc[4];
    #pragma unroll
    for (int c = 0; c < 4; ++c) { sc[c] = __expf(mm[c] - M); L += sc[c] * ll[c]; }
    float o = 0.f;
    #pragma unroll
    for (int c = 0; c < 4; ++c)
        o += O4[(((long)c * 16 + bh) * 784 + q) * 64 + lane] * sc[c];
    o /= L;
    u16 hh, lo2; split_f32(o, hh, lo2);
    long off = ((long)b * 784 + q) * 512 + h * 64 + lane;
    atto[off] = hh; atto[off + ALO] = lo2;
}

// ================= fused: reduce + residual + LN + planar split =================
__global__ __launch_bounds__(256)
void redln(const float* __restrict__ part, long pstride, int ks,
           const float* __restrict__ bias,
           float* __restrict__ z,
           const float* __restrict__ s, const float* __restrict__ b,
           u16* __restrict__ y, long lo)
{
    int wave = threadIdx.x >> 6, lane = threadIdx.x & 63;
    int row = (blockIdx.x << 2) + wave;
    int c0 = lane << 3;
    long base = (long)row * 512 + c0;
    float a[8] = {};
    for (int k = 0; k < ks; ++k) {
        const float* p = part + (long)k * pstride + base;
        float4 p0 = *(const float4*)p, p1 = *(const float4*)(p + 4);
        a[0]+=p0.x; a[1]+=p0.y; a[2]+=p0.z; a[3]+=p0.w;
        a[4]+=p1.x; a[5]+=p1.y; a[6]+=p1.z; a[7]+=p1.w;
    }
    float4 b0 = *(const float4*)(bias + c0), b1 = *(const float4*)(bias + c0 + 4);
    a[0]+=b0.x; a[1]+=b0.y; a[2]+=b0.z; a[3]+=b0.w;
    a[4]+=b1.x; a[5]+=b1.y; a[6]+=b1.z; a[7]+=b1.w;
    float4 z0 = *(const float4*)(z + base), z1 = *(const float4*)(z + base + 4);
    float v[8] = { z0.x+a[0], z0.y+a[1], z0.z+a[2], z0.w+a[3],
                   z1.x+a[4], z1.y+a[5], z1.z+a[6], z1.w+a[7] };
    float4 o0, o1;
    o0.x=v[0]; o0.y=v[1]; o0.z=v[2]; o0.w=v[3];
    o1.x=v[4]; o1.y=v[5]; o1.z=v[6]; o1.w=v[7];
    *(float4*)(z + base) = o0; *(float4*)(z + base + 4) = o1;
    float sum = v[0]+v[1]+v[2]+v[3]+v[4]+v[5]+v[6]+v[7];
    sum = wave_sum(sum);
    float m = sum * (1.0f / 512.0f);
    float var = 0.f;
    float d[8];
    #pragma unroll
    for (int j = 0; j < 8; ++j) { d[j] = v[j] - m; var += d[j]*d[j]; }
    var = wave_sum(var);
    float rstd = 1.0f / sqrtf(var * (1.0f / 512.0f) + 1e-6f);
    u16 hh[8], ll[8];
    #pragma unroll
    for (int j = 0; j < 8; ++j)
        split_f32(d[j] * rstd * s[c0+j] + b[c0+j], hh[j], ll[j]);
    *(uint4*)(y + base) = *(uint4*)hh;
    *(uint4*)(y + lo + base) = *(uint4*)ll;
}

// ================= fused: reduce + bias + posadd + LN (set z) =================
__global__ __launch_bounds__(256)
void redposln(const float* __restrict__ part, long pstride, int ks,
              const float* __restrict__ bias,
              const float* __restrict__ pt, const float* __restrict__ ph,
              const float* __restrict__ pw,
              float* __restrict__ z,
              const float* __restrict__ s, const float* __restrict__ b,
              u16* __restrict__ y, long lo)
{
    int wave = threadIdx.x >> 6, lane = threadIdx.x & 63;
    int row = (blockIdx.x << 2) + wave;
    int c0 = lane << 3;
    long base = (long)row * 512 + c0;
    int r = row % 784;
    int wp = r % 14, hh2 = (r / 14) % 14, tp = r / 196;
    float v[8] = {};
    for (int k = 0; k < ks; ++k) {
        const float* p = part + (long)k * pstride + base;
        float4 p0 = *(const float4*)p, p1 = *(const float4*)(p + 4);
        v[0]+=p0.x; v[1]+=p0.y; v[2]+=p0.z; v[3]+=p0.w;
        v[4]+=p1.x; v[5]+=p1.y; v[6]+=p1.z; v[7]+=p1.w;
    }
    const float* ptp = pt + tp * 512 + c0;
    const float* php = ph + hh2 * 512 + c0;
    const float* pwp = pw + wp * 512 + c0;
    #pragma unroll
    for (int j = 0; j < 8; ++j) v[j] += bias[c0+j] + ptp[j] + php[j] + pwp[j];
    float4 o0, o1;
    o0.x=v[0]; o0.y=v[1]; o0.z=v[2]; o0.w=v[3];
    o1.x=v[4]; o1.y=v[5]; o1.z=v[6]; o1.w=v[7];
    *(float4*)(z + base) = o0; *(float4*)(z + base + 4) = o1;
    float sum = v[0]+v[1]+v[2]+v[3]+v[4]+v[5]+v[6]+v[7];
    sum = wave_sum(sum);
    float m = sum * (1.0f / 512.0f);
    float var = 0.f; float d[8];
    #pragma unroll
    for (int j = 0; j < 8; ++j) { d[j] = v[j] - m; var += d[j]*d[j]; }
    var = wave_sum(var);
    float rstd = 1.0f / sqrtf(var * (1.0f / 512.0f) + 1e-6f);
    u16 hh[8], ll[8];
    #pragma unroll
    for (int j = 0; j < 8; ++j)
        split_f32(d[j] * rstd * s[c0+j] + b[c0+j], hh[j], ll[j]);
    *(uint4*)(y + base) = *(uint4*)hh;
    *(uint4*)(y + lo + base) = *(uint4*)ll;
}

// ================= patchify =================
__global__ void patchify_kernel(const float* __restrict__ video, u16* __restrict__ patches)
{
    long i = (long)blockIdx.x * 256 + threadIdx.x;
    if (i >= (long)TOKq * PINq) return;
    int row = (int)(i / PINq), col = (int)(i - (long)row * PINq);
    int c = col % 3; int q = col / 3;
    int pw = q & 15; q >>= 4;
    int ph = q & 15; int tpin = q >> 4;
    int wp = row % 14; int r2 = row / 14;
    int hp = r2 % 14; r2 /= 14;
    int tp = r2 & 3; int b = r2 >> 2;
    int tt = tp * 4 + tpin;
    int ih = hp * 16 + ph, iw = wp * 16 + pw;
    float v = video[(((long)(b * 16 + tt) * 224 + ih) * 224 + iw) * 3 + c];
    u16 h, l; split_f32(v, h, l);
    patches[i] = h; patches[PLO + i] = l;
}

// ================= z_q gather + SSE + counts =================
__global__ __launch_bounds__(256)
void zq_kernel(const float* __restrict__ cb, const u64* __restrict__ minb,
               const float* __restrict__ ze, u16* __restrict__ zqp, long lo,
               float* __restrict__ part, float* __restrict__ counts,
               float* __restrict__ out_idx)
{
    int tok = blockIdx.x;
    int id = (int)(minb[tok] & 0xFFFFFFFFULL);
    const float* c = cb + (long)id * Dq;
    const float* z = ze + (long)tok * Dq;
    float ss = 0.f;
    for (int d = threadIdx.x; d < Dq; d += 256) {
        float cv = c[d];
        u16 h, l; split_f32(cv, h, l);
        zqp[(long)tok * Dq + d] = h;
        zqp[lo + (long)tok * Dq + d] = l;
        float df = cv - z[d];
        ss += df * df;
    }
    float wsum = wave_sum(ss);
    __shared__ float sw[4];
    if ((threadIdx.x & 63) == 0) sw[threadIdx.x >> 6] = wsum;
    __syncthreads();
    if (threadIdx.x == 0) {
        part[tok] = sw[0] + sw[1] + sw[2] + sw[3];
        atomicAdd(&counts[id], 1.0f);
        out_idx[tok] = (float)id;
    }
}

// ================= scalars =================
__global__ __launch_bounds__(256)
void scalars_kernel(const float* __restrict__ part, const float* __restrict__ counts,
                    float* __restrict__ out)
{
    float se = 0.f;
    for (int t = threadIdx.x; t < TOKq; t += 256) se += part[t];
    float pl = 0.f;
    for (int k = threadIdx.x; k < Kq; k += 256) {
        float p = counts[k] * (1.0f / 1568.0f);
        pl += p * logf(p + 1e-10f);
    }
    float wse = wave_sum(se), wpl = wave_sum(pl);
    __shared__ float s1[4], s2[4];
    if ((threadIdx.x & 63) == 0) { s1[threadIdx.x >> 6] = wse; s2[threadIdx.x >> 6] = wpl; }
    __syncthreads();
    if (threadIdx.x == 0) {
        float sse = s1[0] + s1[1] + s1[2] + s1[3];
        float plo = s2[0] + s2[1] + s2[2] + s2[3];
        float commit = sse / 802816.0f;
        out[RECN + 1568 + 0] = commit;
        out[RECN + 1568 + 1] = commit;
        out[RECN + 1568 + 2] = expf(-plo);
    }
}

// ================= transformer block =================
template<int LVA, int LVF, bool FX2>
static void block_fwd(hipStream_t st, float* z, float* big, float* hbuf,
                      u16* xlnu, u16* qkvu, u16* attou, u16* hbu, u16* wscr,
                      const float* Wqkv, const float* bqkv,
                      const float* Wo, const float* bo,
                      const float* ln2s, const float* ln2b,
                      const float* W1, const float* b1,
                      const float* W2, const float* b2,
                      const float* nls, const float* nlb)
{
    wconv4<<<3072, 256, 0, st>>>(Wqkv, Wo, W1, W2, wscr);
    gemm_bb<4, LVA><<<dim3(600, 1, 1), 256, 0, st>>>(
        xlnu, Dq, XLO, 0, 0,
        wscr, Dq, 786432, 0, 0,
        bqkv, 0, nullptr,
        nullptr, 0, 0, 0,
        qkvu, 1536, QLO,
        nullptr, 0,
        TOKq, 1536, Dq, 1.0f, 1, 1, Dq, 25);
    flash_kernel<FX2><<<dim3(13, 16, 4), 256, 0, st>>>(qkvu, big, big + 3211264L);
    flash_combine<<<3136, 256, 0, st>>>(big, big + 3211264L, attou);
    gemm_bb<0, LVA><<<dim3(200, 1, 4), 256, 0, st>>>(
        attou, Dq, ALO, 0, 0,
        wscr + 1572864, Dq, 262144, 0, 0,
        nullptr, 0, nullptr,
        nullptr, Dq, 0, 0,
        nullptr, 0, 0,
        hbuf, CEXT,
        TOKq, Dq, Dq, 1.0f, 1, 4, 128, 25);
    redln<<<392, 256, 0, st>>>(hbuf, CEXT, 4, bo, z, ln2s, ln2b, xlnu, XLO);
    gemm_bb<2, LVF><<<dim3(800, 1, 1), 256, 0, st>>>(
        xlnu, Dq, XLO, 0, 0,
        wscr + 2097152, Dq, 1048576, 0, 0,
        b1, 0, nullptr,
        nullptr, 0, 0, 0,
        hbu, DFFq, HLO,
        nullptr, 0,
        TOKq, DFFq, Dq, 1.0f, 1, 1, Dq, 25);
    gemm_bb<0, LVF><<<dim3(200, 1, 4), 256, 0, st>>>(
        hbu, DFFq, HLO, 0, 0,
        wscr + 4194304, DFFq, 1048576, 0, 0,
        nullptr, 0, nullptr,
        nullptr, Dq, 0, 0,
        nullptr, 0, 0,
        big, CEXT,
        TOKq, Dq, DFFq, 1.0f, 1, 4, 512, 25);
    redln<<<392, 256, 0, st>>>(big, CEXT, 4, b2, z, nls, nlb, xlnu, XLO);
}

extern "C" void kernel_launch(void* const* d_in, const int* in_sizes, int n_in,
                              void* d_out, int out_size, void* d_ws, size_t ws_size,
                              hipStream_t stream)
{
    (void)in_sizes; (void)n_in; (void)out_size;
    if (ws_size < (size_t)OFF_END * sizeof(float)) return;

    const float* video = (const float*)d_in[0];
    const float* epW   = (const float*)d_in[1];  const float* epb   = (const float*)d_in[2];
    const float* ept   = (const float*)d_in[3];  const float* ephp  = (const float*)d_in[4];
    const float* epwp  = (const float*)d_in[5];
    const float* eln1s = (const float*)d_in[6];  const float* eln1b = (const float*)d_in[7];
    const float* eWqkv = (const float*)d_in[8];  const float* ebqkv = (const float*)d_in[9];
    const float* eWo   = (const float*)d_in[10]; const float* ebo   = (const float*)d_in[11];
    const float* eln2s = (const float*)d_in[12]; const float* eln2b = (const float*)d_in[13];
    const float* eW1   = (const float*)d_in[14]; const float* eb1   = (const float*)d_in[15];
    const float* eW2   = (const float*)d_in[16]; const float* eb2   = (const float*)d_in[17];
    const float* elnfs = (const float*)d_in[18]; const float* elnfb = (const float*)d_in[19];
    const float* ecbW  = (const float*)d_in[20]; const float* ecbb  = (const float*)d_in[21];
    const float* cbook = (const float*)d_in[22];
    const float* dcbW  = (const float*)d_in[23]; const float* dcbb  = (const float*)d_in[24];
    const float* dpt   = (const float*)d_in[25]; const float* dphp  = (const float*)d_in[26];
    const float* dpwp  = (const float*)d_in[27];
    const float* dln1s = (const float*)d_in[28]; const float* dln1b = (const float*)d_in[29];
    const float* dWqkv = (const float*)d_in[30]; const float* dbqkv = (const float*)d_in[31];
    const float* dWo   = (const float*)d_in[32]; const float* dbo   = (const float*)d_in[33];
    const float* dln2s = (const float*)d_in[34]; const float* dln2b = (const float*)d_in[35];
    const float* dW1   = (const float*)d_in[36]; const float* db1   = (const float*)d_in[37];
    const float* dW2   = (const float*)d_in[38]; const float* db2   = (const float*)d_in[39];
    const float* dlnfs = (const float*)d_in[40]; const float* dlnfb = (const float*)d_in[41];
    const float* dpxW  = (const float*)d_in[42]; const float* dpxb  = (const float*)d_in[43];

    float* ws   = (float*)d_ws;
    float* big  = ws + OFF_BIG;
    float* z    = ws + OFF_Z;
    float* xln  = ws + OFF_XLN;
    float* qkv  = ws + OFF_QKV;
    float* atto = ws + OFF_ATTO;
    float* hbuf = ws + OFF_H;
    float* ze   = ws + OFF_ZE;
    float* zq   = ws + OFF_ZQ;
    float* cn   = ws + OFF_CN;
    float* cnt  = ws + OFF_CNT;
    float* part = ws + OFF_PART;
    u64*   minb = (u64*)(ws + OFF_MIN);
    float* out  = (float*)d_out;

    u16* xlnu  = (u16*)xln;
    u16* qkvu  = (u16*)qkv;
    u16* attou = (u16*)atto;
    u16* hbu   = (u16*)hbuf;
    u16* patu  = (u16*)big;
    u16* zqu   = (u16*)zq;
    u16* cbs   = (u16*)qkv;
    u16* wscr  = (u16*)(big + 9633792);

    hipMemsetAsync(cnt, 0, Kq * sizeof(float), stream);
    hipMemsetAsync(minb, 0xFF, TOKq * sizeof(u64), stream);

    // ---- encoder front ----
    patchify_kernel<<<(int)(((long)TOKq * PINq + 255) / 256), 256, 0, stream>>>(video, patu);
    wconv_t<<<dim3(96, 16, 1), 256, 0, stream>>>(epW, Dq, PINq, wscr, 1572864, 0, 0);
    gemm_bb<0, 3><<<dim3(200, 1, 6), 256, 0, stream>>>(
        patu, PINq, PLO, 0, 0,
        wscr, PINq, 1572864, 0, 0,
        nullptr, 0, nullptr,
        nullptr, Dq, 0, 0,
        nullptr, 0, 0,
        big + PLO, CEXT,
        TOKq, Dq, PINq, 1.0f, 1, 6, 512, 25);
    redposln<<<392, 256, 0, stream>>>(big + PLO, CEXT, 6, epb, ept, ephp, epwp,
                                      z, eln1s, eln1b, xlnu, XLO);

    for (int l = 0; l < Lq; ++l) {
        const float* nls = (l < 5) ? eln1s + (l + 1) * Dq : elnfs;
        const float* nlb = (l < 5) ? eln1b + (l + 1) * Dq : elnfb;
        block_fwd<3, 3, false>(stream, z, big, hbuf, xlnu, qkvu, attou, hbu, wscr,
                         eWqkv + (long)l * 3 * Dq * Dq, ebqkv + l * 3 * Dq,
                         eWo + (long)l * Dq * Dq, ebo + l * Dq,
                         eln2s + l * Dq, eln2b + l * Dq,
                         eW1 + (long)l * Dq * DFFq, eb1 + l * DFFq,
                         eW2 + (long)l * DFFq * Dq, eb2 + l * Dq,
                         nls, nlb);
    }

    // ---- encoder head: xlnu already = lnf(z); direct f32+planar epilogue ----
    wconv_t<<<dim3(16, 16, 1), 256, 0, stream>>>(ecbW, Dq, Dq, wscr, 262144, 0, 0);
    gemm_bb<3, 3><<<dim3(200, 1, 1), 256, 0, stream>>>(
        xlnu, Dq, XLO, 0, 0,
        wscr, Dq, 262144, 0, 0,
        ecbb, 0, nullptr,
        ze, Dq, 0, 0,
        zqu, Dq, ZLO,
        nullptr, 0,
        TOKq, Dq, Dq, 1.0f, 1, 1, Dq, 25);

    // ---- VQ: codebook prep (norms + planar) then fused d2 + argmin ----
    cbprep<<<Kq / 4, 256, 0, stream>>>(cbook, cn, cbs);
    gemm_d2w<<<dim3(1600, 1, 1), 256, 0, stream>>>(
        zqu, Dq, ZLO,
        cbs, Dq, CBLO,
        cn, minb,
        TOKq, Kq, Dq, 25);
    zq_kernel<<<TOKq, 256, 0, stream>>>(cbook, minb, ze, zqu, ZLO, part, cnt, out + RECN);
    scalars_kernel<<<1, 256, 0, stream>>>(part, cnt, out);

    // ---- decoder front ----
    wconv_t<<<dim3(16, 16, 1), 256, 0, stream>>>(dcbW, Dq, Dq, wscr, 262144, 0, 0);
    gemm_bb<0, 2><<<dim3(200, 1, 2), 256, 0, stream>>>(
        zqu, Dq, ZLO, 0, 0,
        wscr, Dq, 262144, 0, 0,
        nullptr, 0, nullptr,
        nullptr, Dq, 0, 0,
        nullptr, 0, 0,
        big, CEXT,
        TOKq, Dq, Dq, 1.0f, 1, 2, 256, 25);
    redposln<<<392, 256, 0, stream>>>(big, CEXT, 2, dcbb, dpt, dphp, dpwp,
                                      z, dln1s, dln1b, xlnu, XLO);

    for (int l = 0; l < Lq; ++l) {
        const float* nls = (l < 5) ? dln1s + (l + 1) * Dq : dlnfs;
        const float* nlb = (l < 5) ? dln1b + (l + 1) * Dq : dlnfb;
        block_fwd<2, 1, true>(stream, z, big, hbuf, xlnu, qkvu, attou, hbu, wscr,
                        dWqkv + (long)l * 3 * Dq * Dq, dbqkv + l * 3 * Dq,
                        dWo + (long)l * Dq * Dq, dbo + l * Dq,
                        dln2s + l * Dq, dln2b + l * Dq,
                        dW1 + (long)l * Dq * DFFq, db1 + l * DFFq,
                        dW2 + (long)l * DFFq * Dq, db2 + l * Dq,
                        nls, nlb);
    }

    // ---- decoder head: px GEMM with fused unpatchify scatter ----
    wconv_t<<<dim3(16, 96, 1), 256, 0, stream>>>(dpxW, PINq, Dq, wscr, 1572864, 0, 0);
    gemm_bb<6, 2><<<dim3(1200, 1, 1), 256, 0, stream>>>(
        xlnu, Dq, XLO, 0, 0,
        wscr, Dq, 1572864, 0, 0,
        dpxb, 0, nullptr,
        out, PINq, 0, 0,
        nullptr, 0, 0,
        nullptr, 0,
        TOKq, PINq, Dq, 1.0f, 1, 1, Dq, 25);
}

// Round 19
// 1691.641 us; speedup vs baseline: 1.0272x; 1.0272x over previous
//
#include <hip/hip_runtime.h>
#include <math.h>

// ---- problem dims ----
#define Bq    2
#define Dq    512
#define DFFq  2048
#define Lq    6
#define NHq   8
#define HDq   64
#define Kq    8192
#define Sq    784
#define PINq  3072
#define TOKq  1568
#define RECN  4816896L

// ---- workspace layout (float offsets) ----
#define OFF_BIG  0L
#define SZ_BIG   12845056L
#define OFF_Z    (OFF_BIG + SZ_BIG)
#define OFF_XLN  (OFF_Z    + 802816L)
#define OFF_QKV  (OFF_XLN  + 802816L)
#define OFF_ATTO (OFF_QKV  + 2408448L)
#define OFF_H    (OFF_ATTO + 802816L)
#define OFF_ZE   (OFF_H    + 3211264L)
#define OFF_ZQ   (OFF_ZE   + 802816L)
#define OFF_CN   (OFF_ZQ   + 802816L)
#define OFF_IDX  (OFF_CN   + 8192L)
#define OFF_CNT  (OFF_IDX  + 1568L)
#define OFF_PART (OFF_CNT  + 8192L)
#define OFF_MIN  (OFF_PART + 1568L)
#define OFF_END  (OFF_MIN  + 3136L)

#define CEXT 802816L

typedef short bf16x8 __attribute__((ext_vector_type(8)));
typedef float f32x4  __attribute__((ext_vector_type(4)));
typedef unsigned short u16;
typedef unsigned long long u64;

// plane offsets (u16 elements)
#define XLO 802816L
#define QLO 2408448L
#define ALO 802816L
#define HLO 3211264L
#define PLO 4816896L
#define ZLO 802816L
#define CBLO 4194304L

// ================= helpers =================
__device__ __forceinline__ float wave_sum(float v) {
    #pragma unroll
    for (int o = 32; o; o >>= 1) v += __shfl_xor(v, o);
    return v;
}
__device__ __forceinline__ float gelu_f(float x) {
    float u = 0.7978845608028654f * (x + 0.044715f * x * x * x);
    float a = fabsf(u);
    float t = __expf(-2.0f * a);
    float th = (1.0f - t) / (1.0f + t);
    th = copysignf(th, u);
    return 0.5f * x * (1.0f + th);
}
__device__ __forceinline__ void split_f32(float x, u16& h, u16& l) {
    unsigned u = __float_as_uint(x);
    unsigned t = u + 0x7fffu + ((u >> 16) & 1u);
    h = (u16)(t >> 16);
    float r = x - __uint_as_float((t >> 16) << 16);
    l = (u16)(__float_as_uint(r) >> 16);
}
__device__ __forceinline__ void gload16(const u16* g, u16* l) {
    __builtin_amdgcn_global_load_lds(
        (const __attribute__((address_space(1))) void*)g,
        (__attribute__((address_space(3))) void*)l,
        16, 0, 0);
}

// ================= single weight convert+transpose =================
__global__ __launch_bounds__(256)
void wconv_t(const float* __restrict__ W, int ldw, int Kd,
             u16* __restrict__ WT, long loT, long soW, long soT)
{
    __shared__ u16 Lh[32][33], Ll[32][33];
    const float* Wp = W + (long)blockIdx.z * soW;
    u16* Tp = WT + (long)blockIdx.z * soT;
    int k0 = blockIdx.x << 5, n0 = blockIdx.y << 5;
    int t = threadIdx.x;
    int r = t >> 3, c4 = (t & 7) << 2;
    float4 v = *(const float4*)(Wp + (long)(k0 + r) * ldw + n0 + c4);
    u16 h, l;
    split_f32(v.x, h, l); Lh[c4+0][r] = h; Ll[c4+0][r] = l;
    split_f32(v.y, h, l); Lh[c4+1][r] = h; Ll[c4+1][r] = l;
    split_f32(v.z, h, l); Lh[c4+2][r] = h; Ll[c4+2][r] = l;
    split_f32(v.w, h, l); Lh[c4+3][r] = h; Ll[c4+3][r] = l;
    __syncthreads();
    int n = t >> 3, kc = (t & 7) << 2;
    u16* dst = Tp + (long)(n0 + n) * Kd + k0 + kc;
    u16 oh[4] = {Lh[n][kc], Lh[n][kc+1], Lh[n][kc+2], Lh[n][kc+3]};
    u16 ol[4] = {Ll[n][kc], Ll[n][kc+1], Ll[n][kc+2], Ll[n][kc+3]};
    *(uint2*)dst = *(uint2*)oh;
    *(uint2*)(dst + loT) = *(uint2*)ol;
}

// ================= all-4 layer weights in one launch =================
__global__ __launch_bounds__(256)
void wconv4(const float* __restrict__ Wqkv, const float* __restrict__ Wo,
            const float* __restrict__ W1, const float* __restrict__ W2,
            u16* __restrict__ dst)
{
    __shared__ u16 Lh[32][33], Ll[32][33];
    int id = blockIdx.x;
    const float* W; int ldw, Kd, kblk, nblk; u16* Tp; long loT;
    if (id < 768) {
        int z = id >> 8, rid = id & 255;
        kblk = rid & 15; nblk = rid >> 4;
        W = Wqkv + (long)z * 262144; ldw = 512; Kd = 512;
        Tp = dst + (long)z * 262144; loT = 786432;
    } else if (id < 1024) {
        int rid = id - 768; kblk = rid & 15; nblk = rid >> 4;
        W = Wo; ldw = 512; Kd = 512; Tp = dst + 1572864; loT = 262144;
    } else if (id < 2048) {
        int rid = id - 1024; kblk = rid & 15; nblk = rid >> 4;
        W = W1; ldw = 2048; Kd = 512; Tp = dst + 2097152; loT = 1048576;
    } else {
        int rid = id - 2048; kblk = rid & 63; nblk = rid >> 6;
        W = W2; ldw = 512; Kd = 2048; Tp = dst + 4194304; loT = 1048576;
    }
    int k0 = kblk << 5, n0 = nblk << 5;
    int t = threadIdx.x;
    int r = t >> 3, c4 = (t & 7) << 2;
    float4 v = *(const float4*)(W + (long)(k0 + r) * ldw + n0 + c4);
    u16 h, l;
    split_f32(v.x, h, l); Lh[c4+0][r] = h; Ll[c4+0][r] = l;
    split_f32(v.y, h, l); Lh[c4+1][r] = h; Ll[c4+1][r] = l;
    split_f32(v.z, h, l); Lh[c4+2][r] = h; Ll[c4+2][r] = l;
    split_f32(v.w, h, l); Lh[c4+3][r] = h; Ll[c4+3][r] = l;
    __syncthreads();
    int n = t >> 3, kc = (t & 7) << 2;
    u16* d = Tp + (long)(n0 + n) * Kd + k0 + kc;
    u16 oh[4] = {Lh[n][kc], Lh[n][kc+1], Lh[n][kc+2], Lh[n][kc+3]};
    u16 ol[4] = {Ll[n][kc], Ll[n][kc+1], Ll[n][kc+2], Ll[n][kc+3]};
    *(uint2*)d = *(uint2*)oh;
    *(uint2*)(d + loT) = *(uint2*)ol;
}

// ================= plain planar split =================
__global__ __launch_bounds__(256)
void splitp(const float* __restrict__ X, u16* __restrict__ Y, long lo, long n4)
{
    long i = (long)blockIdx.x * 256 + threadIdx.x;
    if (i >= n4) return;
    float4 v = *(const float4*)(X + i * 4);
    u16 h[4], l[4];
    split_f32(v.x, h[0], l[0]); split_f32(v.y, h[1], l[1]);
    split_f32(v.z, h[2], l[2]); split_f32(v.w, h[3], l[3]);
    *(uint2*)(Y + i * 4) = *(uint2*)h;
    *(uint2*)(Y + lo + i * 4) = *(uint2*)l;
}

// ================= 64x64 MFMA GEMM, BK=64, chunk-swizzled LDS =================
// LV=3: bf16x3. LV=2: A hi+lo, B hi. LV=1: pure bf16.
template<int MATH, int LV>
__global__ __launch_bounds__(256)
void gemm_bb(const u16* __restrict__ A, long rsA, long loA, long soA, long siA,
             const u16* __restrict__ B, long rsB, long loB, long soB, long siB,
             const float* __restrict__ bias, long siBias,
             const float* __restrict__ extra,
             float* __restrict__ Cf, int ldc, long soC, long siC,
             u16* __restrict__ Cb, int rsC, long loC,
             float* __restrict__ part, long pstride,
             int M, int N, int K, float alpha,
             int bdiv, int ksplit, int klen, int gx)
{
    constexpr int OFF_BH = (LV >= 2) ? 8192 : 4096;
    __shared__ u16 SH[LV == 3 ? 16384 : (LV == 2 ? 12288 : 8192)];
    const int zb2 = blockIdx.z;
    const int zk = zb2 % ksplit, zb = zb2 / ksplit;
    const int zo = zb / bdiv, zi = zb - zo * bdiv;
    A += zo * soA + zi * siA;
    B += zo * soB + zi * siB;
    const float* bi = bias ? bias + zi * siBias : nullptr;

    const int nwg = gridDim.x;
    int orig = blockIdx.x;
    int qq = nwg >> 3, rr = nwg & 7;
    int xcd = orig & 7, sidx = orig >> 3;
    int wgid = (xcd < rr ? xcd * (qq + 1) : rr * (qq + 1) + (xcd - rr) * qq) + sidx;
    const int m0 = (wgid % gx) << 6, n0 = (wgid / gx) << 6;

    const int t = threadIdx.x;
    const int kbeg = zk * klen;
    int kend = kbeg + klen; if (kend > K) kend = K;

    const int w = t >> 6, lane = t & 63;
    const int wm = w >> 1, wn = w & 1;
    const int l15 = lane & 15, g = lane >> 4;
    const int wq = w << 9;

    const int csrc = ((t & 3) + ((t >> 3) & 7)) & 3;
    int arow = m0 + (t >> 2); if (arow > M - 1) arow = M - 1;
    const u16* Apr = A + (long)arow * rsA + (csrc << 3);
    const u16* Bpr = B + (long)(n0 + (t >> 2)) * rsB + (csrc << 3);

    f32x4 acc[2][2] = {};

    for (int k0 = kbeg; k0 < kend; k0 += 64) {
        gload16(Apr + k0,            &SH[wq]);
        if (LV >= 2) gload16(Apr + k0 + loA,      &SH[4096 + wq]);
        gload16(Bpr + k0,            &SH[OFF_BH + wq]);
        if (LV == 3) gload16(Bpr + k0 + loB, &SH[12288 + wq]);
        gload16(Apr + k0 + 32,       &SH[2048 + wq]);
        if (LV >= 2) gload16(Apr + k0 + 32 + loA, &SH[4096 + 2048 + wq]);
        gload16(Bpr + k0 + 32,       &SH[OFF_BH + 2048 + wq]);
        if (LV == 3) gload16(Bpr + k0 + 32 + loB, &SH[12288 + 2048 + wq]);
        __syncthreads();

        #pragma unroll
        for (int sub = 0; sub < 2; ++sub) {
            const int so = sub << 11;
            bf16x8 ah[2], al2[2], bh2[2], bl2[2];
            #pragma unroll
            for (int mi = 0; mi < 2; ++mi) {
                int row = (wm << 5) + (mi << 4) + l15;
                int off = (row << 5) + (((g - (row >> 1)) & 3) << 3);
                ah[mi]  = *(const bf16x8*)&SH[so + off];
                if (LV >= 2) al2[mi] = *(const bf16x8*)&SH[4096 + so + off];
            }
            #pragma unroll
            for (int ni = 0; ni < 2; ++ni) {
                int row = (wn << 5) + (ni << 4) + l15;
                int off = (row << 5) + (((g - (row >> 1)) & 3) << 3);
                bh2[ni] = *(const bf16x8*)&SH[OFF_BH + so + off];
                if (LV == 3) bl2[ni] = *(const bf16x8*)&SH[12288 + so + off];
            }
            #pragma unroll
            for (int mi = 0; mi < 2; ++mi)
                #pragma unroll
                for (int ni = 0; ni < 2; ++ni) {
                    acc[mi][ni] = __builtin_amdgcn_mfma_f32_16x16x32_bf16(ah[mi], bh2[ni], acc[mi][ni], 0, 0, 0);
                    if (LV == 3) acc[mi][ni] = __builtin_amdgcn_mfma_f32_16x16x32_bf16(ah[mi], bl2[ni], acc[mi][ni], 0, 0, 0);
                    if (LV >= 2) acc[mi][ni] = __builtin_amdgcn_mfma_f32_16x16x32_bf16(al2[mi], bh2[ni], acc[mi][ni], 0, 0, 0);
                }
        }
        __syncthreads();
    }

    if (ksplit > 1) {
        float* P = part + (long)zk * pstride + zo * soC + zi * siC;
        #pragma unroll
        for (int mi = 0; mi < 2; ++mi)
            #pragma unroll
            for (int ni = 0; ni < 2; ++ni) {
                int gn = n0 + (wn << 5) + (ni << 4) + l15;
                if (gn >= N) continue;
                int gmb = m0 + (wm << 5) + (mi << 4) + (g << 2);
                #pragma unroll
                for (int r = 0; r < 4; ++r) {
                    int gm = gmb + r;
                    if (gm < M) P[(long)gm * ldc + gn] = acc[mi][ni][r];
                }
            }
        return;
    }
    if (MATH == 0) {
        float* Co = Cf + zo * soC + zi * siC;
        #pragma unroll
        for (int mi = 0; mi < 2; ++mi)
            #pragma unroll
            for (int ni = 0; ni < 2; ++ni) {
                int gn = n0 + (wn << 5) + (ni << 4) + l15;
                if (gn >= N) continue;
                int gmb = m0 + (wm << 5) + (mi << 4) + (g << 2);
                #pragma unroll
                for (int r = 0; r < 4; ++r) {
                    int gm = gmb + r;
                    if (gm >= M) continue;
                    Co[(long)gm * ldc + gn] = alpha * acc[mi][ni][r] + (bi ? bi[gn] : 0.0f);
                }
            }
    } else {
        u16* Cu = Cb + zo * soC + zi * siC;
        #pragma unroll
        for (int mi = 0; mi < 2; ++mi)
            #pragma unroll
            for (int ni = 0; ni < 2; ++ni) {
                int gn = n0 + (wn << 5) + (ni << 4) + l15;
                if (gn >= N) continue;
                int gmb = m0 + (wm << 5) + (mi << 4) + (g << 2);
                #pragma unroll
                for (int r = 0; r < 4; ++r) {
                    int gm = gmb + r;
                    if (gm >= M) continue;
                    float v = acc[mi][ni][r] + bi[gn];
                    if (MATH == 2) v = gelu_f(v);
                    u16 h, l; split_f32(v, h, l);
                    Cu[(long)gm * rsC + gn] = h;
                    Cu[(long)gm * rsC + gn + loC] = l;
                }
            }
    }
}

// ================= d2 VQ GEMM: 64x128 block, bf16x3, fused argmin =================
__global__ __launch_bounds__(256)
void gemm_d2w(const u16* __restrict__ A, long rsA, long loA,
              const u16* __restrict__ B, long rsB, long loB,
              const float* __restrict__ extra, u64* __restrict__ mb,
              int M, int N, int K, int gx)
{
    __shared__ u16 SH[24576];
    const int nwg = gridDim.x;
    int orig = blockIdx.x;
    int qq = nwg >> 3, rr = nwg & 7;
    int xcd = orig & 7, sidx = orig >> 3;
    int wgid = (xcd < rr ? xcd * (qq + 1) : rr * (qq + 1) + (xcd - rr) * qq) + sidx;
    const int m0 = (wgid % gx) << 6, n0 = (wgid / gx) << 7;

    const int t = threadIdx.x;
    const int w = t >> 6, lane = t & 63;
    const int wm = w >> 1, wn = w & 1;
    const int l15 = lane & 15, g = lane >> 4;
    const int wq = w << 9;

    const int csrc = ((t & 3) + ((t >> 3) & 7)) & 3;
    int arow = m0 + (t >> 2); if (arow > M - 1) arow = M - 1;
    const u16* Apr = A + (long)arow * rsA + (csrc << 3);
    const u16* Bpr0 = B + (long)(n0 + (t >> 2)) * rsB + (csrc << 3);
    const u16* Bpr1 = B + (long)(n0 + 64 + (t >> 2)) * rsB + (csrc << 3);

    f32x4 acc[2][4] = {};

    for (int k0 = 0; k0 < K; k0 += 64) {
        gload16(Apr + k0,             &SH[wq]);
        gload16(Apr + k0 + 32,        &SH[2048 + wq]);
        gload16(Apr + k0 + loA,       &SH[4096 + wq]);
        gload16(Apr + k0 + 32 + loA,  &SH[4096 + 2048 + wq]);
        gload16(Bpr0 + k0,            &SH[8192 + wq]);
        gload16(Bpr1 + k0,            &SH[8192 + 2048 + wq]);
        gload16(Bpr0 + k0 + 32,       &SH[12288 + wq]);
        gload16(Bpr1 + k0 + 32,       &SH[12288 + 2048 + wq]);
        gload16(Bpr0 + k0 + loB,      &SH[16384 + wq]);
        gload16(Bpr1 + k0 + loB,      &SH[16384 + 2048 + wq]);
        gload16(Bpr0 + k0 + 32 + loB, &SH[20480 + wq]);
        gload16(Bpr1 + k0 + 32 + loB, &SH[20480 + 2048 + wq]);
        __syncthreads();

        #pragma unroll
        for (int sub = 0; sub < 2; ++sub) {
            const int soA = sub << 11;
            const int soB = sub << 12;
            bf16x8 ah[2], al2[2], bh2[4], bl2[4];
            #pragma unroll
            for (int mi = 0; mi < 2; ++mi) {
                int row = (wm << 5) + (mi << 4) + l15;
                int off = (row << 5) + (((g - (row >> 1)) & 3) << 3);
                ah[mi]  = *(const bf16x8*)&SH[soA + off];
                al2[mi] = *(const bf16x8*)&SH[4096 + soA + off];
            }
            #pragma unroll
            for (int ni = 0; ni < 4; ++ni) {
                int row = (wn << 6) + (ni << 4) + l15;
                int off = (row << 5) + (((g - (row >> 1)) & 3) << 3);
                bh2[ni] = *(const bf16x8*)&SH[8192 + soB + off];
                bl2[ni] = *(const bf16x8*)&SH[16384 + soB + off];
            }
            #pragma unroll
            for (int mi = 0; mi < 2; ++mi)
                #pragma unroll
                for (int ni = 0; ni < 4; ++ni) {
                    acc[mi][ni] = __builtin_amdgcn_mfma_f32_16x16x32_bf16(ah[mi],  bh2[ni], acc[mi][ni], 0, 0, 0);
                    acc[mi][ni] = __builtin_amdgcn_mfma_f32_16x16x32_bf16(ah[mi],  bl2[ni], acc[mi][ni], 0, 0, 0);
                    acc[mi][ni] = __builtin_amdgcn_mfma_f32_16x16x32_bf16(al2[mi], bh2[ni], acc[mi][ni], 0, 0, 0);
                }
        }
        __syncthreads();
    }

    #pragma unroll
    for (int mi = 0; mi < 2; ++mi) {
        #pragma unroll
        for (int r = 0; r < 4; ++r) {
            u64 best = 0xFFFFFFFFFFFFFFFFULL;
            #pragma unroll
            for (int ni = 0; ni < 4; ++ni) {
                int gn = n0 + (wn << 6) + (ni << 4) + l15;
                float v = extra[gn] - 2.0f * acc[mi][ni][r];
                unsigned ub = __float_as_uint(v);
                ub = ub ^ ((ub >> 31) ? 0xFFFFFFFFu : 0x80000000u);
                u64 pk = ((u64)ub << 32) | (unsigned)gn;
                best = pk < best ? pk : best;
            }
            #pragma unroll
            for (int sft = 1; sft <= 8; sft <<= 1) {
                u64 o = __shfl_xor(best, sft);
                best = o < best ? o : best;
            }
            if (l15 == 0) {
                int gm = m0 + (wm << 5) + (mi << 4) + (g << 2) + r;
                if (gm < M) atomicMin(&mb[gm], best);
            }
        }
    }
}

// ================= flash attention, KV-split x4 =================
#define KP 72
#define VP 40
#define CHR 196
template<bool X2>
__global__ __launch_bounds__(256)
void flash_kernel(const u16* __restrict__ qkv, float* __restrict__ O4, float* __restrict__ ML)
{
    __shared__ u16 Kh[32 * KP], Kl[32 * KP];
    __shared__ u16 Vh[64 * VP], Vl[64 * VP];
    __shared__ u16 Ph[64 * VP], Pl[64 * VP];

    const int qb = blockIdx.x, bh = blockIdx.y, ch = blockIdx.z;
    const int b = bh >> 3, h = bh & 7;
    const int jbeg = ch * CHR, jend = jbeg + CHR;
    const int t = threadIdx.x, w = t >> 6, lane = t & 63;
    const int l15 = lane & 15, g = lane >> 4;
    const long base = (long)b * 784 * 1536;
    const u16* Qg = qkv + base + h * 64;
    const u16* Kg = qkv + base + 512 + h * 64;
    const u16* Vg = qkv + base + 1024 + h * 64;

    const int q0 = qb << 6;
    int qr = q0 + w * 16 + l15; if (qr > 783) qr = 783;
    const u16* Qp = Qg + (long)qr * 1536 + g * 8;
    bf16x8 qh[2], ql[2];
    qh[0] = *(const bf16x8*)(Qp);
    qh[1] = *(const bf16x8*)(Qp + 32);
    ql[0] = *(const bf16x8*)(Qp + QLO);
    ql[1] = *(const bf16x8*)(Qp + QLO + 32);

    f32x4 O[4] = {};
    float m_[4] = {-1e30f, -1e30f, -1e30f, -1e30f};
    float l_[4] = {};

    const int srow = t >> 3, sc = (t & 7) << 3;

    for (int j0 = jbeg; j0 < jend; j0 += 32) {
        {
            int jr = j0 + srow;
            if (jr < jend) {
                const u16* Kp = Kg + (long)jr * 1536 + sc;
                *(uint4*)&Kh[srow * KP + sc] = *(const uint4*)(Kp);
                if (!X2) *(uint4*)&Kl[srow * KP + sc] = *(const uint4*)(Kp + QLO);
                const u16* Vp = Vg + (long)jr * 1536 + sc;
                u16 th[8], tl[8];
                *(uint4*)th = *(const uint4*)Vp;
                if (!X2) *(uint4*)tl = *(const uint4*)(Vp + QLO);
                #pragma unroll
                for (int e = 0; e < 8; ++e) {
                    Vh[(sc + e) * VP + srow] = th[e];
                    if (!X2) Vl[(sc + e) * VP + srow] = tl[e];
                }
            } else {
                uint4 zz = {0, 0, 0, 0};
                *(uint4*)&Kh[srow * KP + sc] = zz;
                if (!X2) *(uint4*)&Kl[srow * KP + sc] = zz;
                #pragma unroll
                for (int e = 0; e < 8; ++e) {
                    Vh[(sc + e) * VP + srow] = 0;
                    if (!X2) Vl[(sc + e) * VP + srow] = 0;
                }
            }
        }
        __syncthreads();

        f32x4 S[2] = {};
        #pragma unroll
        for (int f = 0; f < 2; ++f) {
            #pragma unroll
            for (int ks = 0; ks < 2; ++ks) {
                bf16x8 kh = *(const bf16x8*)&Kh[(f * 16 + l15) * KP + ks * 32 + g * 8];
                S[f] = __builtin_amdgcn_mfma_f32_16x16x32_bf16(qh[ks], kh, S[f], 0, 0, 0);
                if (!X2) {
                    bf16x8 kl = *(const bf16x8*)&Kl[(f * 16 + l15) * KP + ks * 32 + g * 8];
                    S[f] = __builtin_amdgcn_mfma_f32_16x16x32_bf16(qh[ks], kl, S[f], 0, 0, 0);
                }
                S[f] = __builtin_amdgcn_mfma_f32_16x16x32_bf16(ql[ks], kh, S[f], 0, 0, 0);
            }
        }

        float p[2][4];
        #pragma unroll
        for (int f = 0; f < 2; ++f) {
            bool ok = (j0 + f * 16 + l15) < jend;
            #pragma unroll
            for (int r = 0; r < 4; ++r)
                p[f][r] = ok ? S[f][r] * 0.125f : -1e30f;
        }
        #pragma unroll
        for (int r = 0; r < 4; ++r) {
            float pm = fmaxf(p[0][r], p[1][r]);
            pm = fmaxf(pm, __shfl_xor(pm, 1)); pm = fmaxf(pm, __shfl_xor(pm, 2));
            pm = fmaxf(pm, __shfl_xor(pm, 4)); pm = fmaxf(pm, __shfl_xor(pm, 8));
            float mn = fmaxf(m_[r], pm);
            float scl = __expf(m_[r] - mn);
            float rs = 0.f;
            #pragma unroll
            for (int f = 0; f < 2; ++f) { float e = __expf(p[f][r] - mn); p[f][r] = e; rs += e; }
            rs += __shfl_xor(rs, 1); rs += __shfl_xor(rs, 2);
            rs += __shfl_xor(rs, 4); rs += __shfl_xor(rs, 8);
            l_[r] = l_[r] * scl + rs;
            m_[r] = mn;
            O[0][r] *= scl; O[1][r] *= scl; O[2][r] *= scl; O[3][r] *= scl;
        }

        #pragma unroll
        for (int f = 0; f < 2; ++f)
            #pragma unroll
            for (int r = 0; r < 4; ++r) {
                u16 hh, ll; split_f32(p[f][r], hh, ll);
                int row = w * 16 + g * 4 + r;
                Ph[row * VP + f * 16 + l15] = hh;
                Pl[row * VP + f * 16 + l15] = ll;
            }

        bf16x8 pah = *(const bf16x8*)&Ph[(w * 16 + l15) * VP + g * 8];
        bf16x8 pal = *(const bf16x8*)&Pl[(w * 16 + l15) * VP + g * 8];
        #pragma unroll
        for (int f = 0; f < 4; ++f) {
            bf16x8 vh = *(const bf16x8*)&Vh[(f * 16 + l15) * VP + g * 8];
            O[f] = __builtin_amdgcn_mfma_f32_16x16x32_bf16(pah, vh, O[f], 0, 0, 0);
            O[f] = __builtin_amdgcn_mfma_f32_16x16x32_bf16(pal, vh, O[f], 0, 0, 0);
            if (!X2) {
                bf16x8 vl = *(const bf16x8*)&Vl[(f * 16 + l15) * VP + g * 8];
                O[f] = __builtin_amdgcn_mfma_f32_16x16x32_bf16(pah, vl, O[f], 0, 0, 0);
            }
        }
        __syncthreads();
    }

    #pragma unroll
    for (int r = 0; r < 4; ++r) {
        int q = q0 + w * 16 + g * 4 + r;
        if (q >= 784) continue;
        long rowi = ((long)ch * 16 + bh) * 784 + q;
        if (l15 == 0) { ML[rowi * 2] = m_[r]; ML[rowi * 2 + 1] = l_[r]; }
        #pragma unroll
        for (int f = 0; f < 4; ++f)
            O4[rowi * 64 + f * 16 + l15] = O[f][r];
    }
}

// ================= flash combine: merge 4 KV-chunk partials =================
__global__ __launch_bounds__(256)
void flash_combine(const float* __restrict__ O4, const float* __restrict__ ML,
                   u16* __restrict__ atto)
{
    int wave = threadIdx.x >> 6, lane = threadIdx.x & 63;
    int row = (blockIdx.x << 2) + wave;
    int bh = row / 784, q = row - bh * 784;
    int b = bh >> 3, h = bh & 7;
    float mm[4], ll[4];
    float M = -1e30f;
    #pragma unroll
    for (int c = 0; c < 4; ++c) {
        long ri = ((long)c * 16 + bh) * 784 + q;
        mm[c] = ML[ri * 2]; ll[c] = ML[ri * 2 + 1];
        M = fmaxf(M, mm[c]);
    }
    float L = 0.f, sc[4];
    #pragma unroll
    for (int c = 0; c < 4; ++c) { sc[c] = __expf(mm[c] - M); L += sc[c] * ll[c]; }
    float o = 0.f;
    #pragma unroll
    for (int c = 0; c < 4; ++c)
        o += O4[(((long)c * 16 + bh) * 784 + q) * 64 + lane] * sc[c];
    o /= L;
    u16 hh, lo2; split_f32(o, hh, lo2);
    long off = ((long)b * 784 + q) * 512 + h * 64 + lane;
    atto[off] = hh; atto[off + ALO] = lo2;
}

// ================= split-K reduce =================
// 3: Cf=s+b AND planar; 4: planar gelu(s+b)
template<int MATH>
__global__ __launch_bounds__(256)
void reduce_k(const float* __restrict__ part, long pstride, int ks,
              const float* __restrict__ bias, int ldc,
              float* __restrict__ Cf, u16* __restrict__ Cb, long loC, long total)
{
    long i = (long)blockIdx.x * 256 + threadIdx.x;
    if (i >= total) return;
    float s = 0.f;
    for (int k = 0; k < ks; ++k) s += part[(long)k * pstride + i];
    int col = (int)(i % ldc);
    float v = s + (bias ? bias[col] : 0.0f);
    if (MATH == 3) { Cf[i] = v; u16 h, l; split_f32(v, h, l); Cb[i] = h; Cb[i + loC] = l; }
    else { float g = gelu_f(v); u16 h, l; split_f32(g, h, l); Cb[i] = h; Cb[i + loC] = l; }
}

// ================= fused: reduce + residual + LN + planar split =================
__global__ __launch_bounds__(256)
void redln(const float* __restrict__ part, long pstride, int ks,
           const float* __restrict__ bias,
           float* __restrict__ z,
           const float* __restrict__ s, const float* __restrict__ b,
           u16* __restrict__ y, long lo)
{
    int wave = threadIdx.x >> 6, lane = threadIdx.x & 63;
    int row = (blockIdx.x << 2) + wave;
    int c0 = lane << 3;
    long base = (long)row * 512 + c0;
    float a[8] = {};
    for (int k = 0; k < ks; ++k) {
        const float* p = part + (long)k * pstride + base;
        float4 p0 = *(const float4*)p, p1 = *(const float4*)(p + 4);
        a[0]+=p0.x; a[1]+=p0.y; a[2]+=p0.z; a[3]+=p0.w;
        a[4]+=p1.x; a[5]+=p1.y; a[6]+=p1.z; a[7]+=p1.w;
    }
    float4 b0 = *(const float4*)(bias + c0), b1 = *(const float4*)(bias + c0 + 4);
    a[0]+=b0.x; a[1]+=b0.y; a[2]+=b0.z; a[3]+=b0.w;
    a[4]+=b1.x; a[5]+=b1.y; a[6]+=b1.z; a[7]+=b1.w;
    float4 z0 = *(const float4*)(z + base), z1 = *(const float4*)(z + base + 4);
    float v[8] = { z0.x+a[0], z0.y+a[1], z0.z+a[2], z0.w+a[3],
                   z1.x+a[4], z1.y+a[5], z1.z+a[6], z1.w+a[7] };
    float4 o0, o1;
    o0.x=v[0]; o0.y=v[1]; o0.z=v[2]; o0.w=v[3];
    o1.x=v[4]; o1.y=v[5]; o1.z=v[6]; o1.w=v[7];
    *(float4*)(z + base) = o0; *(float4*)(z + base + 4) = o1;
    float sum = v[0]+v[1]+v[2]+v[3]+v[4]+v[5]+v[6]+v[7];
    sum = wave_sum(sum);
    float m = sum * (1.0f / 512.0f);
    float var = 0.f;
    float d[8];
    #pragma unroll
    for (int j = 0; j < 8; ++j) { d[j] = v[j] - m; var += d[j]*d[j]; }
    var = wave_sum(var);
    float rstd = 1.0f / sqrtf(var * (1.0f / 512.0f) + 1e-6f);
    u16 hh[8], ll[8];
    #pragma unroll
    for (int j = 0; j < 8; ++j)
        split_f32(d[j] * rstd * s[c0+j] + b[c0+j], hh[j], ll[j]);
    *(uint4*)(y + base) = *(uint4*)hh;
    *(uint4*)(y + lo + base) = *(uint4*)ll;
}

// ================= fused: reduce + bias + posadd + LN (set z) =================
__global__ __launch_bounds__(256)
void redposln(const float* __restrict__ part, long pstride, int ks,
              const float* __restrict__ bias,
              const float* __restrict__ pt, const float* __restrict__ ph,
              const float* __restrict__ pw,
              float* __restrict__ z,
              const float* __restrict__ s, const float* __restrict__ b,
              u16* __restrict__ y, long lo)
{
    int wave = threadIdx.x >> 6, lane = threadIdx.x & 63;
    int row = (blockIdx.x << 2) + wave;
    int c0 = lane << 3;
    long base = (long)row * 512 + c0;
    int r = row % 784;
    int wp = r % 14, hh2 = (r / 14) % 14, tp = r / 196;
    float v[8] = {};
    for (int k = 0; k < ks; ++k) {
        const float* p = part + (long)k * pstride + base;
        float4 p0 = *(const float4*)p, p1 = *(const float4*)(p + 4);
        v[0]+=p0.x; v[1]+=p0.y; v[2]+=p0.z; v[3]+=p0.w;
        v[4]+=p1.x; v[5]+=p1.y; v[6]+=p1.z; v[7]+=p1.w;
    }
    const float* ptp = pt + tp * 512 + c0;
    const float* php = ph + hh2 * 512 + c0;
    const float* pwp = pw + wp * 512 + c0;
    #pragma unroll
    for (int j = 0; j < 8; ++j) v[j] += bias[c0+j] + ptp[j] + php[j] + pwp[j];
    float4 o0, o1;
    o0.x=v[0]; o0.y=v[1]; o0.z=v[2]; o0.w=v[3];
    o1.x=v[4]; o1.y=v[5]; o1.z=v[6]; o1.w=v[7];
    *(float4*)(z + base) = o0; *(float4*)(z + base + 4) = o1;
    float sum = v[0]+v[1]+v[2]+v[3]+v[4]+v[5]+v[6]+v[7];
    sum = wave_sum(sum);
    float m = sum * (1.0f / 512.0f);
    float var = 0.f; float d[8];
    #pragma unroll
    for (int j = 0; j < 8; ++j) { d[j] = v[j] - m; var += d[j]*d[j]; }
    var = wave_sum(var);
    float rstd = 1.0f / sqrtf(var * (1.0f / 512.0f) + 1e-6f);
    u16 hh[8], ll[8];
    #pragma unroll
    for (int j = 0; j < 8; ++j)
        split_f32(d[j] * rstd * s[c0+j] + b[c0+j], hh[j], ll[j]);
    *(uint4*)(y + base) = *(uint4*)hh;
    *(uint4*)(y + lo + base) = *(uint4*)ll;
}

// ================= codebook norms =================
__global__ __launch_bounds__(256)
void cnorm_kernel(const float* __restrict__ cb, float* __restrict__ cn)
{
    int wave = threadIdx.x >> 6, lane = threadIdx.x & 63;
    int row = (blockIdx.x << 2) + wave;
    if (row >= Kq) return;
    const float* cr = cb + (long)row * Dq;
    float4 v0 = *(const float4*)(cr + (lane << 2));
    float4 v1 = *(const float4*)(cr + 256 + (lane << 2));
    float ss = v0.x*v0.x+v0.y*v0.y+v0.z*v0.z+v0.w*v0.w
             + v1.x*v1.x+v1.y*v1.y+v1.z*v1.z+v1.w*v1.w;
    ss = wave_sum(ss);
    if (lane == 0) cn[row] = ss;
}

// ================= patchify / unpatchify =================
__global__ void patchify_kernel(const float* __restrict__ video, u16* __restrict__ patches)
{
    long i = (long)blockIdx.x * 256 + threadIdx.x;
    if (i >= (long)TOKq * PINq) return;
    int row = (int)(i / PINq), col = (int)(i - (long)row * PINq);
    int c = col % 3; int q = col / 3;
    int pw = q & 15; q >>= 4;
    int ph = q & 15; int tpin = q >> 4;
    int wp = row % 14; int r2 = row / 14;
    int hp = r2 % 14; r2 /= 14;
    int tp = r2 & 3; int b = r2 >> 2;
    int tt = tp * 4 + tpin;
    int ih = hp * 16 + ph, iw = wp * 16 + pw;
    float v = video[(((long)(b * 16 + tt) * 224 + ih) * 224 + iw) * 3 + c];
    u16 h, l; split_f32(v, h, l);
    patches[i] = h; patches[PLO + i] = l;
}

__global__ void unpatchify_kernel(const float* __restrict__ px, float* __restrict__ out)
{
    long o = (long)blockIdx.x * 256 + threadIdx.x;
    if (o >= RECN) return;
    int c = (int)(o % 3); long r = o / 3;
    int iw = (int)(r % 224); r /= 224;
    int ih = (int)(r % 224); r /= 224;
    int tt = (int)(r % 16); int b = (int)(r / 16);
    int tp = tt >> 2, tpin = tt & 3;
    int hp = ih >> 4, ph = ih & 15;
    int wp = iw >> 4, pw = iw & 15;
    long prow = ((long)(b * 4 + tp) * 14 + hp) * 14 + wp;
    int pcol = ((tpin * 16 + ph) * 16 + pw) * 3 + c;
    out[o] = px[prow * PINq + pcol];
}

// ================= z_q gather + SSE + counts =================
__global__ __launch_bounds__(256)
void zq_kernel(const float* __restrict__ cb, const u64* __restrict__ minb,
               const float* __restrict__ ze, u16* __restrict__ zqp, long lo,
               float* __restrict__ part, float* __restrict__ counts,
               float* __restrict__ out_idx)
{
    int tok = blockIdx.x;
    int id = (int)(minb[tok] & 0xFFFFFFFFULL);
    const float* c = cb + (long)id * Dq;
    const float* z = ze + (long)tok * Dq;
    float ss = 0.f;
    for (int d = threadIdx.x; d < Dq; d += 256) {
        float cv = c[d];
        u16 h, l; split_f32(cv, h, l);
        zqp[(long)tok * Dq + d] = h;
        zqp[lo + (long)tok * Dq + d] = l;
        float df = cv - z[d];
        ss += df * df;
    }
    float wsum = wave_sum(ss);
    __shared__ float sw[4];
    if ((threadIdx.x & 63) == 0) sw[threadIdx.x >> 6] = wsum;
    __syncthreads();
    if (threadIdx.x == 0) {
        part[tok] = sw[0] + sw[1] + sw[2] + sw[3];
        atomicAdd(&counts[id], 1.0f);
        out_idx[tok] = (float)id;
    }
}

// ================= scalars =================
__global__ __launch_bounds__(256)
void scalars_kernel(const float* __restrict__ part, const float* __restrict__ counts,
                    float* __restrict__ out)
{
    float se = 0.f;
    for (int t = threadIdx.x; t < TOKq; t += 256) se += part[t];
    float pl = 0.f;
    for (int k = threadIdx.x; k < Kq; k += 256) {
        float p = counts[k] * (1.0f / 1568.0f);
        pl += p * logf(p + 1e-10f);
    }
    float wse = wave_sum(se), wpl = wave_sum(pl);
    __shared__ float s1[4], s2[4];
    if ((threadIdx.x & 63) == 0) { s1[threadIdx.x >> 6] = wse; s2[threadIdx.x >> 6] = wpl; }
    __syncthreads();
    if (threadIdx.x == 0) {
        float sse = s1[0] + s1[1] + s1[2] + s1[3];
        float plo = s2[0] + s2[1] + s2[2] + s2[3];
        float commit = sse / 802816.0f;
        out[RECN + 1568 + 0] = commit;
        out[RECN + 1568 + 1] = commit;
        out[RECN + 1568 + 2] = expf(-plo);
    }
}

// ================= transformer block =================
template<int LVA, int LVF, bool FX2>
static void block_fwd(hipStream_t st, float* z, float* big, float* hbuf,
                      u16* xlnu, u16* qkvu, u16* attou, u16* hbu, u16* wscr,
                      const float* Wqkv, const float* bqkv,
                      const float* Wo, const float* bo,
                      const float* ln2s, const float* ln2b,
                      const float* W1, const float* b1,
                      const float* W2, const float* b2,
                      const float* nls, const float* nlb)
{
    wconv4<<<3072, 256, 0, st>>>(Wqkv, Wo, W1, W2, wscr);
    gemm_bb<4, LVA><<<dim3(600, 1, 1), 256, 0, st>>>(
        xlnu, Dq, XLO, 0, 0,
        wscr, Dq, 786432, 0, 0,
        bqkv, 0, nullptr,
        nullptr, 0, 0, 0,
        qkvu, 1536, QLO,
        nullptr, 0,
        TOKq, 1536, Dq, 1.0f, 1, 1, Dq, 25);
    // flash: KV-split x4 into big (O4 + ML), then combine
    flash_kernel<FX2><<<dim3(13, 16, 4), 256, 0, st>>>(qkvu, big, big + 3211264L);
    flash_combine<<<3136, 256, 0, st>>>(big, big + 3211264L, attou);
    gemm_bb<0, LVA><<<dim3(200, 1, 4), 256, 0, st>>>(
        attou, Dq, ALO, 0, 0,
        wscr + 1572864, Dq, 262144, 0, 0,
        nullptr, 0, nullptr,
        nullptr, Dq, 0, 0,
        nullptr, 0, 0,
        hbuf, CEXT,
        TOKq, Dq, Dq, 1.0f, 1, 4, 128, 25);
    redln<<<392, 256, 0, st>>>(hbuf, CEXT, 4, bo, z, ln2s, ln2b, xlnu, XLO);
    gemm_bb<2, LVF><<<dim3(800, 1, 1), 256, 0, st>>>(
        xlnu, Dq, XLO, 0, 0,
        wscr + 2097152, Dq, 1048576, 0, 0,
        b1, 0, nullptr,
        nullptr, 0, 0, 0,
        hbu, DFFq, HLO,
        nullptr, 0,
        TOKq, DFFq, Dq, 1.0f, 1, 1, Dq, 25);
    gemm_bb<0, LVF><<<dim3(200, 1, 4), 256, 0, st>>>(
        hbu, DFFq, HLO, 0, 0,
        wscr + 4194304, DFFq, 1048576, 0, 0,
        nullptr, 0, nullptr,
        nullptr, Dq, 0, 0,
        nullptr, 0, 0,
        big, CEXT,
        TOKq, Dq, DFFq, 1.0f, 1, 4, 512, 25);
    redln<<<392, 256, 0, st>>>(big, CEXT, 4, b2, z, nls, nlb, xlnu, XLO);
}

extern "C" void kernel_launch(void* const* d_in, const int* in_sizes, int n_in,
                              void* d_out, int out_size, void* d_ws, size_t ws_size,
                              hipStream_t stream)
{
    (void)in_sizes; (void)n_in; (void)out_size;
    if (ws_size < (size_t)OFF_END * sizeof(float)) return;

    const float* video = (const float*)d_in[0];
    const float* epW   = (const float*)d_in[1];  const float* epb   = (const float*)d_in[2];
    const float* ept   = (const float*)d_in[3];  const float* ephp  = (const float*)d_in[4];
    const float* epwp  = (const float*)d_in[5];
    const float* eln1s = (const float*)d_in[6];  const float* eln1b = (const float*)d_in[7];
    const float* eWqkv = (const float*)d_in[8];  const float* ebqkv = (const float*)d_in[9];
    const float* eWo   = (const float*)d_in[10]; const float* ebo   = (const float*)d_in[11];
    const float* eln2s = (const float*)d_in[12]; const float* eln2b = (const float*)d_in[13];
    const float* eW1   = (const float*)d_in[14]; const float* eb1   = (const float*)d_in[15];
    const float* eW2   = (const float*)d_in[16]; const float* eb2   = (const float*)d_in[17];
    const float* elnfs = (const float*)d_in[18]; const float* elnfb = (const float*)d_in[19];
    const float* ecbW  = (const float*)d_in[20]; const float* ecbb  = (const float*)d_in[21];
    const float* cbook = (const float*)d_in[22];
    const float* dcbW  = (const float*)d_in[23]; const float* dcbb  = (const float*)d_in[24];
    const float* dpt   = (const float*)d_in[25]; const float* dphp  = (const float*)d_in[26];
    const float* dpwp  = (const float*)d_in[27];
    const float* dln1s = (const float*)d_in[28]; const float* dln1b = (const float*)d_in[29];
    const float* dWqkv = (const float*)d_in[30]; const float* dbqkv = (const float*)d_in[31];
    const float* dWo   = (const float*)d_in[32]; const float* dbo   = (const float*)d_in[33];
    const float* dln2s = (const float*)d_in[34]; const float* dln2b = (const float*)d_in[35];
    const float* dW1   = (const float*)d_in[36]; const float* db1   = (const float*)d_in[37];
    const float* dW2   = (const float*)d_in[38]; const float* db2   = (const float*)d_in[39];
    const float* dlnfs = (const float*)d_in[40]; const float* dlnfb = (const float*)d_in[41];
    const float* dpxW  = (const float*)d_in[42]; const float* dpxb  = (const float*)d_in[43];

    float* ws   = (float*)d_ws;
    float* big  = ws + OFF_BIG;
    float* z    = ws + OFF_Z;
    float* xln  = ws + OFF_XLN;
    float* qkv  = ws + OFF_QKV;
    float* atto = ws + OFF_ATTO;
    float* hbuf = ws + OFF_H;
    float* ze   = ws + OFF_ZE;
    float* zq   = ws + OFF_ZQ;
    float* cn   = ws + OFF_CN;
    float* cnt  = ws + OFF_CNT;
    float* part = ws + OFF_PART;
    u64*   minb = (u64*)(ws + OFF_MIN);
    float* out  = (float*)d_out;

    u16* xlnu  = (u16*)xln;
    u16* qkvu  = (u16*)qkv;
    u16* attou = (u16*)atto;
    u16* hbu   = (u16*)hbuf;
    u16* patu  = (u16*)big;
    u16* zqu   = (u16*)zq;
    u16* cbs   = (u16*)qkv;
    u16* wscr  = (u16*)(big + 9633792);

    hipMemsetAsync(cnt, 0, Kq * sizeof(float), stream);
    hipMemsetAsync(minb, 0xFF, TOKq * sizeof(u64), stream);
    cnorm_kernel<<<Kq / 4, 256, 0, stream>>>(cbook, cn);

    // ---- encoder front ----
    patchify_kernel<<<(int)(((long)TOKq * PINq + 255) / 256), 256, 0, stream>>>(video, patu);
    wconv_t<<<dim3(96, 16, 1), 256, 0, stream>>>(epW, Dq, PINq, wscr, 1572864, 0, 0);
    gemm_bb<0, 3><<<dim3(200, 1, 6), 256, 0, stream>>>(
        patu, PINq, PLO, 0, 0,
        wscr, PINq, 1572864, 0, 0,
        nullptr, 0, nullptr,
        nullptr, Dq, 0, 0,
        nullptr, 0, 0,
        big + PLO, CEXT,
        TOKq, Dq, PINq, 1.0f, 1, 6, 512, 25);
    redposln<<<392, 256, 0, stream>>>(big + PLO, CEXT, 6, epb, ept, ephp, epwp,
                                      z, eln1s, eln1b, xlnu, XLO);

    for (int l = 0; l < Lq; ++l) {
        const float* nls = (l < 5) ? eln1s + (l + 1) * Dq : elnfs;
        const float* nlb = (l < 5) ? eln1b + (l + 1) * Dq : elnfb;
        block_fwd<3, 3, false>(stream, z, big, hbuf, xlnu, qkvu, attou, hbu, wscr,
                         eWqkv + (long)l * 3 * Dq * Dq, ebqkv + l * 3 * Dq,
                         eWo + (long)l * Dq * Dq, ebo + l * Dq,
                         eln2s + l * Dq, eln2b + l * Dq,
                         eW1 + (long)l * Dq * DFFq, eb1 + l * DFFq,
                         eW2 + (long)l * DFFq * Dq, eb2 + l * Dq,
                         nls, nlb);
    }

    // ---- encoder head: xlnu already = lnf(z) ----
    wconv_t<<<dim3(16, 16, 1), 256, 0, stream>>>(ecbW, Dq, Dq, wscr, 262144, 0, 0);
    gemm_bb<0, 3><<<dim3(200, 1, 2), 256, 0, stream>>>(
        xlnu, Dq, XLO, 0, 0,
        wscr, Dq, 262144, 0, 0,
        nullptr, 0, nullptr,
        nullptr, Dq, 0, 0,
        nullptr, 0, 0,
        big, CEXT,
        TOKq, Dq, Dq, 1.0f, 1, 2, 256, 25);
    reduce_k<3><<<(CEXT + 255) / 256, 256, 0, stream>>>(big, CEXT, 2, ecbb, Dq, ze, zqu, ZLO, CEXT);

    // ---- VQ: fused d2 + argmin, 64x128 tile (encoder-exact bf16x3) ----
    splitp<<<(int)(((long)Kq * Dq / 4 + 255) / 256), 256, 0, stream>>>(cbook, cbs, CBLO, (long)Kq * Dq / 4);
    gemm_d2w<<<dim3(1600, 1, 1), 256, 0, stream>>>(
        zqu, Dq, ZLO,
        cbs, Dq, CBLO,
        cn, minb,
        TOKq, Kq, Dq, 25);
    zq_kernel<<<TOKq, 256, 0, stream>>>(cbook, minb, ze, zqu, ZLO, part, cnt, out + RECN);
    scalars_kernel<<<1, 256, 0, stream>>>(part, cnt, out);

    // ---- decoder front ----
    wconv_t<<<dim3(16, 16, 1), 256, 0, stream>>>(dcbW, Dq, Dq, wscr, 262144, 0, 0);
    gemm_bb<0, 2><<<dim3(200, 1, 2), 256, 0, stream>>>(
        zqu, Dq, ZLO, 0, 0,
        wscr, Dq, 262144, 0, 0,
        nullptr, 0, nullptr,
        nullptr, Dq, 0, 0,
        nullptr, 0, 0,
        big, CEXT,
        TOKq, Dq, Dq, 1.0f, 1, 2, 256, 25);
    redposln<<<392, 256, 0, stream>>>(big, CEXT, 2, dcbb, dpt, dphp, dpwp,
                                      z, dln1s, dln1b, xlnu, XLO);

    for (int l = 0; l < Lq; ++l) {
        const float* nls = (l < 5) ? dln1s + (l + 1) * Dq : dlnfs;
        const float* nlb = (l < 5) ? dln1b + (l + 1) * Dq : dlnfb;
        block_fwd<2, 1, true>(stream, z, big, hbuf, xlnu, qkvu, attou, hbu, wscr,
                        dWqkv + (long)l * 3 * Dq * Dq, dbqkv + l * 3 * Dq,
                        dWo + (long)l * Dq * Dq, dbo + l * Dq,
                        dln2s + l * Dq, dln2b + l * Dq,
                        dW1 + (long)l * Dq * DFFq, db1 + l * DFFq,
                        dW2 + (long)l * DFFq * Dq, db2 + l * Dq,
                        nls, nlb);
    }

    // ---- decoder head: xlnu = lnf(z) ----
    wconv_t<<<dim3(16, 96, 1), 256, 0, stream>>>(dpxW, PINq, Dq, wscr, 1572864, 0, 0);
    gemm_bb<0, 2><<<dim3(1200, 1, 1), 256, 0, stream>>>(
        xlnu, Dq, XLO, 0, 0,
        wscr, Dq, 1572864, 0, 0,
        dpxb, 0, nullptr,
        big, PINq, 0, 0,
        nullptr, 0, 0,
        nullptr, 0,
        TOKq, PINq, Dq, 1.0f, 1, 1, Dq, 25);
    unpatchify_kernel<<<(int)((RECN + 255) / 256), 256, 0, stream>>>(big, out);
}